// Round 7
// baseline (298.012 us; speedup 1.0000x reference)
//
#include <hip/hip_runtime.h>
#include <math.h>

#define HID 2048
#define NH 32
#define NKV 8
#define HD 64
#define BB 2
#define SS 2048
#define MTOT (BB * SS) // 4096

typedef __bf16 bf16;
typedef __bf16 bf16x8 __attribute__((ext_vector_type(8)));
typedef __bf16 bf16x4 __attribute__((ext_vector_type(4)));
typedef float f32x4 __attribute__((ext_vector_type(4)));

#define MFMA16(a, b, c) __builtin_amdgcn_mfma_f32_16x16x32_bf16((a), (b), (c), 0, 0, 0)

__device__ __forceinline__ void load_lds16(const void* g, void* l) {
  __builtin_amdgcn_global_load_lds((const __attribute__((address_space(1))) void*)g,
                                   (__attribute__((address_space(3))) void*)l, 16, 0, 0);
}

#define FENCE() asm volatile("" ::: "memory")
// Tile-top sync: counted vmcnt (never 0 in main loop) + lgkmcnt(0) so this
// wave's ds_reads have COMPLETED before it enters the barrier (orders them
// against other waves' post-barrier global_load_lds writebacks), then barrier.
#define SYNC_VM(N) do { FENCE(); \
  asm volatile("s_waitcnt vmcnt(" #N ") lgkmcnt(0)" ::: "memory"); \
  __builtin_amdgcn_s_barrier(); FENCE(); } while (0)

// ---------------- fused fp32 -> bf16 convert (all 5 tensors, one launch) ----------------
__global__ void cvt_all(const float* __restrict__ hs, const float* __restrict__ Wq,
                        const float* __restrict__ Wk, const float* __restrict__ Wv,
                        const float* __restrict__ Wo,
                        bf16* __restrict__ A_b, bf16* __restrict__ Wq_b,
                        bf16* __restrict__ Wk_b, bf16* __restrict__ Wv_b,
                        bf16* __restrict__ Wo_b) {
  int bid = blockIdx.x;
  const float* src;
  bf16* dst;
  if (bid < 8192)       { src = hs; dst = A_b; }
  else if (bid < 12288) { src = Wq; dst = Wq_b; bid -= 8192; }
  else if (bid < 13312) { src = Wk; dst = Wk_b; bid -= 12288; }
  else if (bid < 14336) { src = Wv; dst = Wv_b; bid -= 13312; }
  else                  { src = Wo; dst = Wo_b; bid -= 14336; }
  int i = (bid * 256 + threadIdx.x) * 4;
  float4 v = *(const float4*)(src + i);
  bf16x4 o;
  o[0] = (bf16)v.x; o[1] = (bf16)v.y; o[2] = (bf16)v.z; o[3] = (bf16)v.w;
  *(bf16x4*)(dst + i) = o;
}

// ---------------- BK=32 pipelined core (verified round 4/5): 256x128, 8 waves ----------------
// 72 KB -> 2 WG/CU (16 waves) -- the best measured waves/CU config (3.8 TF/CU).
__device__ __forceinline__ void gemm_core256x128(const char* Agc, const char* Bgc,
                                                 char* lds, f32x4 (&acc)[4][4]) {
  constexpr int ABYTES = 16384;     // A tile bytes (256 x 32 bf16)
  constexpr int BUFB = 24576;       // + B tile (128 x 32 bf16)
  constexpr int NT = HID / 32;      // 64 K-tiles

  const int tid = threadIdx.x;
  const int w = tid >> 6, lane = tid & 63;
  const int l16 = lane & 15, quad = lane >> 4;
  const int wr = w >> 1, wc = w & 1;
  const int wb = w * 1024;          // wave-uniform LDS staging base

  const int cu = (tid & 7) ^ ((tid >> 3) & 7);
  const int srcR0 = 2 * (tid >> 3) + (cu >> 2);   // 0..127
  const int srcC = (cu & 3) * 16;
  const char* gA = Agc + (size_t)srcR0 * (HID * 2) + srcC;
  const char* gB = Bgc + (size_t)srcR0 * (HID * 2) + srcC;

  const int acg16 = ((((l16 & 1) << 2) | quad) ^ ((l16 >> 1) & 7)) * 16;
  const int aoff = (wr * 32 + (l16 >> 1)) * 128 + acg16;
  const int boff = ABYTES + (wc * 32 + (l16 >> 1)) * 128 + acg16;

#pragma unroll
  for (int t0 = 0; t0 < 2; ++t0) {
    char* lb = lds + t0 * BUFB;
    load_lds16(gA + t0 * 64, lb + wb);
    load_lds16(gA + (size_t)128 * (HID * 2) + t0 * 64, lb + 8192 + wb);
    load_lds16(gB + t0 * 64, lb + ABYTES + wb);
  }

  char* cur = lds;
  char* stg = lds + 2 * BUFB;
  for (int kt = 0; kt < NT; ++kt) {
    SYNC_VM(3);
    const int ks = (kt + 2 < NT) ? (kt + 2) * 64 : (NT - 1) * 64;

    load_lds16(gA + ks, stg + wb);
    load_lds16(gA + (size_t)128 * (HID * 2) + ks, stg + 8192 + wb);
    load_lds16(gB + ks, stg + ABYTES + wb);
    FENCE();

    bf16x8 af[4], bfr[4];
#pragma unroll
    for (int ni = 0; ni < 4; ++ni)
      bfr[ni] = *(const bf16x8*)(cur + boff + ni * 1024);
#pragma unroll
    for (int mi = 0; mi < 4; ++mi)
      af[mi] = *(const bf16x8*)(cur + aoff + mi * 1024);
    __builtin_amdgcn_s_setprio(1);
#pragma unroll
    for (int mi = 0; mi < 4; ++mi)
#pragma unroll
      for (int ni = 0; ni < 4; ++ni)
        acc[mi][ni] = MFMA16(af[mi], bfr[ni], acc[mi][ni]);
    __builtin_amdgcn_s_setprio(0);

    cur = (cur == lds + 2 * BUFB) ? lds : cur + BUFB;
    stg = (stg == lds + 2 * BUFB) ? lds : stg + BUFB;
  }
  asm volatile("s_waitcnt vmcnt(0)" ::: "memory");
}

// ---------------- BK=64 core with 2-phase K-step (EXPERIMENT, gemm_out only) ----------------
// Same verified invariants as round 6's k64 core: 3 rotating 48 KB buffers,
// SYNC_VM(6) at step top (tile kt resident, kt+1's 6 loads in flight),
// lgkmcnt(0)+barrier publishes buf (kt+2)%3 fully-read before overwrite.
// NEW: the K-step body is split into two raw-barrier phases, each
// {stage-issue || 8 ds_reads || 16 MFMA} -- T3-lite interleave so reads of
// some waves overlap MFMAs of others within the single resident WG. The mid
// barrier is raw (__builtin_amdgcn_s_barrier -- NO waitcnt drain) and
// uniform; all reads/stages still complete/issue within the step, so the
// tile-top invariants are unchanged.
__device__ __forceinline__ void gemm_core_k64p(const char* Agc, const char* Bgc,
                                               char* lds, f32x4 (&acc)[4][4]) {
  constexpr int ABYTES = 32768;   // A tile: 256 rows x 64 cols bf16
  constexpr int BUFB = 49152;     // + B tile: 128 rows x 64 cols bf16
  constexpr int NT = HID / 64;    // 32 K-steps

  const int tid = threadIdx.x;
  const int w = tid >> 6, lane = tid & 63;
  const int l16 = lane & 15, quad = lane >> 4;
  const int wr = w >> 1, wc = w & 1;
  const int wb = w * 1024;        // wave-uniform LDS staging base

  // staging (verified r6): wave w, load j -> row = w*8 + j*64 + (lane>>3),
  // logical chunk = (lane&7) ^ ((lane>>3)&7); inverse swizzle on global src.
  const int cu = (lane & 7) ^ ((lane >> 3) & 7);
  const char* gA = Agc + (size_t)(w * 8 + (lane >> 3)) * 4096 + cu * 16;
  const char* gB = Bgc + (size_t)(w * 8 + (lane >> 3)) * 4096 + cu * 16;

  // ds_read: row r chunk c at (c ^ (r&7))*16; frag (mi|ni, ks) below.
  const int aswz = l16 & 7;
  const int a_k0 = ((0 + quad) ^ aswz) * 16;   // ks = 0
  const int a_k1 = ((4 + quad) ^ aswz) * 16;   // ks = 1
  const int arow = (wr * 64 + l16) * 128;
  const int brow = (wc * 64 + l16) * 128;

  // prologue: stage K-steps 0 and 1 (6 loads per wave per K-step: 4 A + 2 B)
#pragma unroll
  for (int t0 = 0; t0 < 2; ++t0) {
    char* lb = lds + t0 * BUFB;
#pragma unroll
    for (int j = 0; j < 4; ++j)
      load_lds16(gA + (size_t)j * (64 * 4096) + t0 * 128, lb + wb + j * 8192);
#pragma unroll
    for (int j = 0; j < 2; ++j)
      load_lds16(gB + (size_t)j * (64 * 4096) + t0 * 128, lb + ABYTES + wb + j * 8192);
  }

  char* cur = lds;
  char* stg = lds + 2 * BUFB;
  for (int kt = 0; kt < NT; ++kt) {
    SYNC_VM(6);
    const int ks = (kt + 2 < NT) ? (kt + 2) : (NT - 1);
    const size_t ko = (size_t)ks * 128;
    const char* Ac = cur;
    const char* Bc = cur + ABYTES;

    // ---- phase 0: stage A-half of kt+2, read ks=0 frags, 16 MFMA ----
#pragma unroll
    for (int j = 0; j < 4; ++j)
      load_lds16(gA + (size_t)j * (64 * 4096) + ko, stg + wb + j * 8192);
    FENCE();
    bf16x8 af0[4], bf0[4];
#pragma unroll
    for (int ni = 0; ni < 4; ++ni)
      bf0[ni] = *(const bf16x8*)(Bc + brow + ni * 2048 + a_k0);
#pragma unroll
    for (int mi = 0; mi < 4; ++mi)
      af0[mi] = *(const bf16x8*)(Ac + arow + mi * 2048 + a_k0);
    __builtin_amdgcn_s_setprio(1);
#pragma unroll
    for (int mi = 0; mi < 4; ++mi)
#pragma unroll
      for (int ni = 0; ni < 4; ++ni)
        acc[mi][ni] = MFMA16(af0[mi], bf0[ni], acc[mi][ni]);
    __builtin_amdgcn_s_setprio(0);
    FENCE();
    __builtin_amdgcn_s_barrier();   // raw mid-phase barrier: no waitcnt drain
    FENCE();

    // ---- phase 1: stage B-half of kt+2, read ks=1 frags, 16 MFMA ----
#pragma unroll
    for (int j = 0; j < 2; ++j)
      load_lds16(gB + (size_t)j * (64 * 4096) + ko, stg + ABYTES + wb + j * 8192);
    FENCE();
    bf16x8 af1[4], bf1[4];
#pragma unroll
    for (int ni = 0; ni < 4; ++ni)
      bf1[ni] = *(const bf16x8*)(Bc + brow + ni * 2048 + a_k1);
#pragma unroll
    for (int mi = 0; mi < 4; ++mi)
      af1[mi] = *(const bf16x8*)(Ac + arow + mi * 2048 + a_k1);
    __builtin_amdgcn_s_setprio(1);
#pragma unroll
    for (int mi = 0; mi < 4; ++mi)
#pragma unroll
      for (int ni = 0; ni < 4; ++ni)
        acc[mi][ni] = MFMA16(af1[mi], bf1[ni], acc[mi][ni]);
    __builtin_amdgcn_s_setprio(0);

    cur = (cur == lds + 2 * BUFB) ? lds : cur + BUFB;
    stg = (stg == lds + 2 * BUFB) ? lds : stg + BUFB;
  }
  asm volatile("s_waitcnt vmcnt(0)" ::: "memory");
}

// ---------------- fused QKV projection + RoPE epilogue (R5 config restored) ----------------
#define QSCALE 0.1803368801f
#define L2B 0.4152410118f  // log2(10000)/32
__global__ __launch_bounds__(512, 4) void gemm_qkv(const bf16* __restrict__ A,
                                                   const bf16* __restrict__ Wq,
                                                   const bf16* __restrict__ Wk,
                                                   const bf16* __restrict__ Wv,
                                                   bf16* __restrict__ Qb,
                                                   bf16* __restrict__ Kb,
                                                   bf16* __restrict__ Vt) {
  __shared__ __align__(16) char lds[3 * 24576];  // 72 KB -> 2 WG/CU (16 waves)
  const int tileM = blockIdx.x * 256;
  const int n0 = blockIdx.y * 128;
  const bf16* Wp;
  int mode;
  if (n0 < HID) { Wp = Wq + (size_t)n0 * HID; mode = 0; }
  else if (n0 < HID + 512) { Wp = Wk + (size_t)(n0 - HID) * HID; mode = 1; }
  else { Wp = Wv + (size_t)(n0 - HID - 512) * HID; mode = 2; }

  f32x4 acc[4][4];
#pragma unroll
  for (int i = 0; i < 4; ++i)
#pragma unroll
    for (int j = 0; j < 4; ++j) acc[i][j] = (f32x4){0.f, 0.f, 0.f, 0.f};

  gemm_core256x128((const char*)(A + (size_t)tileM * HID), (const char*)Wp, lds, acc);

  const int tid = threadIdx.x;
  const int w = tid >> 6, lane = tid & 63;
  const int l16 = lane & 15, quad = lane >> 4;
  const int wr = w >> 1, wc = w & 1;
  const int mbase = tileM + wr * 64;
  const int cb = n0 + wc * 64;  // 64-aligned -> wave col span = one head

  if (mode == 2) {
    // V: transposed layout [b,kvh,d,s]
#pragma unroll
    for (int mi = 0; mi < 4; ++mi)
#pragma unroll
      for (int ni = 0; ni < 4; ++ni)
#pragma unroll
        for (int r = 0; r < 4; ++r) {
          int grow = mbase + mi * 16 + quad * 4 + r;
          int b = grow >> 11, spos = grow & (SS - 1);
          int nv = cb + ni * 16 + l16 - (HID + 512);
          Vt[(((size_t)(b * NKV + (nv >> 6))) * HD + (nv & 63)) * SS + spos] =
              (bf16)acc[mi][ni][r];
        }
  } else {
    // Q or K: RoPE in fp32 regs; pairs (ni=0,ni=2) at freq l16, (1,3) at l16+16.
    const float inv0 = __builtin_amdgcn_exp2f(-(float)l16 * L2B);
    const float inv1 = __builtin_amdgcn_exp2f(-(float)(l16 + 16) * L2B);
#pragma unroll
    for (int mi = 0; mi < 4; ++mi) {
#pragma unroll
      for (int r = 0; r < 4; ++r) {
        int grow = mbase + mi * 16 + quad * 4 + r;
        int b = grow >> 11, spos = grow & (SS - 1);
        float sn0, cs0, sn1, cs1;
        sincosf((float)spos * inv0, &sn0, &cs0);
        sincosf((float)spos * inv1, &sn1, &cs1);
        float a0 = acc[mi][0][r], a1 = acc[mi][1][r];
        float a2 = acc[mi][2][r], a3 = acc[mi][3][r];
        float o0 = a0 * cs0 - a2 * sn0;
        float o2 = a2 * cs0 + a0 * sn0;
        float o1 = a1 * cs1 - a3 * sn1;
        float o3 = a3 * cs1 + a1 * sn1;
        if (mode == 0) {
          bf16* qp = Qb + (size_t)grow * HID + cb + l16;
          qp[0]  = (bf16)(o0 * QSCALE);
          qp[16] = (bf16)(o1 * QSCALE);
          qp[32] = (bf16)(o2 * QSCALE);
          qp[48] = (bf16)(o3 * QSCALE);
        } else {
          int kvh = (cb - HID) >> 6;
          bf16* kp = Kb + ((size_t)(b * NKV + kvh) * SS + spos) * HD + l16;
          kp[0]  = (bf16)o0;
          kp[16] = (bf16)o1;
          kp[32] = (bf16)o2;
          kp[48] = (bf16)o3;
        }
      }
    }
  }
}

// ---------------- output projection (grid 16x16 = 256 blocks = 1/CU, BK=64 2-phase) ----------------
__global__ __launch_bounds__(512, 2) void gemm_out(const bf16* __restrict__ A,
                                                   const bf16* __restrict__ Wo,
                                                   float* __restrict__ out) {
  __shared__ __align__(16) char lds[3 * 49152];  // 144 KB -> 1 WG/CU
  const int tileM = blockIdx.x * 256;
  const int n0 = blockIdx.y * 128;
  f32x4 acc[4][4];
#pragma unroll
  for (int i = 0; i < 4; ++i)
#pragma unroll
    for (int j = 0; j < 4; ++j) acc[i][j] = (f32x4){0.f, 0.f, 0.f, 0.f};

  gemm_core_k64p((const char*)(A + (size_t)tileM * HID),
                 (const char*)(Wo + (size_t)n0 * HID), lds, acc);

  const int tid = threadIdx.x;
  const int w = tid >> 6, lane = tid & 63;
  const int l16 = lane & 15, quad = lane >> 4;
  const int wr = w >> 1, wc = w & 1;
#pragma unroll
  for (int mi = 0; mi < 4; ++mi)
#pragma unroll
    for (int ni = 0; ni < 4; ++ni)
#pragma unroll
      for (int r = 0; r < 4; ++r) {
        int grow = tileM + wr * 64 + mi * 16 + quad * 4 + r;
        int gcol = n0 + wc * 64 + ni * 16 + l16;
        out[(size_t)grow * HID + gcol] = acc[mi][ni][r];
      }
}

// ---------------- flash attention v6: 128 q-rows per block (verified round 5) ----------------
#define PSTR 72
__global__ __launch_bounds__(256, 3) void attn(const bf16* __restrict__ Qb,
                                               const bf16* __restrict__ Kb,
                                               const bf16* __restrict__ Vt,
                                               bf16* __restrict__ Ctx) {
  __shared__ bf16 Ktile[2][64 * 64];
  __shared__ bf16 Vtile[2][64 * 64];
  __shared__ bf16 Pbuf[4][32 * PSTR];   // per wave: rows 0-15 = A, 16-31 = B
  const int tid = threadIdx.x;
  const int w = tid >> 6, lane = tid & 63;
  const int l16 = lane & 15, quad = lane >> 4;
  const int bh = blockIdx.y, b = bh >> 5, h = bh & 31, kvh = h >> 2;
  bf16* Pw = &Pbuf[w][0];
  const char* Kslice = (const char*)(Kb + ((size_t)(b * NKV + kvh)) * SS * HD);
  const char* Vslice = (const char*)(Vt + ((size_t)(b * NKV + kvh)) * HD * SS);
  const int qrel = w * 16 + l16;        // 0..63 within each 64-row subtile

  const int srow = (lane >> 3) & 7;
  const int pchunk = ((lane & 7) ^ srow) << 4;
  const int so = ((quad ^ (l16 & 7)) << 4);
  const int so2 = so ^ 64;

  const int xA = (int)blockIdx.x;       // 0..7

  int cur = 0;
  {
#pragma unroll
    for (int i = 0; i < 2; ++i) {
      const int r = w * 16 + i * 8 + srow;
      load_lds16(Kslice + (size_t)r * 128 + pchunk,
                 (char*)Ktile[0] + (w * 16 + i * 8) * 128);
      load_lds16(Vslice + (size_t)r * 4096 + pchunk,
                 (char*)Vtile[0] + (w * 16 + i * 8) * 128);
    }
  }

  for (int t = 0; t < 2; ++t) {
    const int X = t ? (15 - xA) : xA;   // 128-row superblock index
    const int qA = X * 128 + qrel;
    const int ktmax = 2 * X + 1;        // last kv tile (64 keys each)

    const bf16* QpA = Qb + ((size_t)(b * SS + qA)) * HID + h * HD + quad * 8;
    bf16x8 qa0 = *(const bf16x8*)QpA;
    bf16x8 qa1 = *(const bf16x8*)(QpA + 32);
    const bf16* QpB = QpA + (size_t)64 * HID;
    bf16x8 qbB0 = *(const bf16x8*)QpB;
    bf16x8 qbB1 = *(const bf16x8*)(QpB + 32);

    float lA = 0.f, lB = 0.f;
    f32x4 oA[4], oB[4];
#pragma unroll
    for (int d = 0; d < 4; ++d) {
      oA[d] = (f32x4){0.f, 0.f, 0.f, 0.f};
      oB[d] = (f32x4){0.f, 0.f, 0.f, 0.f};
    }

    for (int kt = 0; kt <= ktmax; ++kt) {
      __syncthreads();   // cur tile ready (staged a full compute phase ago)

      const bool have_next = (kt < ktmax) || (t == 0);
      if (have_next) {
        const int nkb = (kt < ktmax) ? (kt + 1) * 64 : 0;  // last: tile 0 for pass 1
        const int nb = cur ^ 1;
#pragma unroll
        for (int i = 0; i < 2; ++i) {
          const int r = w * 16 + i * 8 + srow;
          load_lds16(Kslice + (size_t)(nkb + r) * 128 + pchunk,
                     (char*)Ktile[nb] + (w * 16 + i * 8) * 128);
          load_lds16(Vslice + (size_t)r * 4096 + (size_t)nkb * 2 + pchunk,
                     (char*)Vtile[nb] + (w * 16 + i * 8) * 128);
        }
      }

      const char* Kc = (const char*)Ktile[cur] + l16 * 128;
      const char* Vc = (const char*)Vtile[cur] + l16 * 128;
      const bool skipA = (kt == ktmax);       // A fully masked on last tile
      const bool diagA = (kt == ktmax - 1);   // kt == 2X
      const bool diagB = (kt == ktmax);       // kt == 2X+1

#pragma unroll
      for (int nt = 0; nt < 4; ++nt) {
        bf16x8 kf0 = *(const bf16x8*)(Kc + nt * 2048 + so);
        bf16x8 kf1 = *(const bf16x8*)(Kc + nt * 2048 + so2);
        const int krel = nt * 16 + quad * 4;

        bf16x4 pkA;
        if (skipA) {
          pkA[0] = (bf16)0.f; pkA[1] = (bf16)0.f;
          pkA[2] = (bf16)0.f; pkA[3] = (bf16)0.f;
        } else {
          f32x4 s = {0.f, 0.f, 0.f, 0.f};
          s = MFMA16(kf0, qa0, s);   // S^T: row = key, col = q (l16)
          s = MFMA16(kf1, qa1, s);
          if (diagA) {
#pragma unroll
            for (int r = 0; r < 4; ++r) {
              float p = (krel + r > qrel) ? 0.f : __builtin_amdgcn_exp2f(s[r]);
              lA += p;
              pkA[r] = (bf16)p;
            }
          } else {
#pragma unroll
            for (int r = 0; r < 4; ++r) {
              float p = __builtin_amdgcn_exp2f(s[r]);
              lA += p;
              pkA[r] = (bf16)p;
            }
          }
        }
        *(bf16x4*)&Pw[l16 * PSTR + krel] = pkA;

        f32x4 sB = {0.f, 0.f, 0.f, 0.f};
        sB = MFMA16(kf0, qbB0, sB);
        sB = MFMA16(kf1, qbB1, sB);
        bf16x4 pkB;
        if (diagB) {
#pragma unroll
          for (int r = 0; r < 4; ++r) {
            float p = (krel + r > qrel) ? 0.f : __builtin_amdgcn_exp2f(sB[r]);
            lB += p;
            pkB[r] = (bf16)p;
          }
        } else {
#pragma unroll
          for (int r = 0; r < 4; ++r) {
            float p = __builtin_amdgcn_exp2f(sB[r]);
            lB += p;
            pkB[r] = (bf16)p;
          }
        }
        *(bf16x4*)&Pw[(16 + l16) * PSTR + krel] = pkB;
      }

      bf16x8 pA0 = *(const bf16x8*)&Pw[l16 * PSTR + quad * 8];
      bf16x8 pA1 = *(const bf16x8*)&Pw[l16 * PSTR + 32 + quad * 8];
      bf16x8 pB0 = *(const bf16x8*)&Pw[(16 + l16) * PSTR + quad * 8];
      bf16x8 pB1 = *(const bf16x8*)&Pw[(16 + l16) * PSTR + 32 + quad * 8];
#pragma unroll
      for (int dn = 0; dn < 4; ++dn) {
        bf16x8 v0 = *(const bf16x8*)(Vc + dn * 2048 + so);
        bf16x8 v1 = *(const bf16x8*)(Vc + dn * 2048 + so2);
        oA[dn] = MFMA16(v0, pA0, oA[dn]);  // O^T: row = d, col = q
        oA[dn] = MFMA16(v1, pA1, oA[dn]);
        oB[dn] = MFMA16(v0, pB0, oB[dn]);
        oB[dn] = MFMA16(v1, pB1, oB[dn]);
      }
      cur ^= 1;
    }

    lA += __shfl_xor(lA, 16);
    lA += __shfl_xor(lA, 32);
    lB += __shfl_xor(lB, 16);
    lB += __shfl_xor(lB, 32);
    const float invA = 1.0f / lA;
    const float invB = 1.0f / lB;
    bf16* CpA = Ctx + ((size_t)(b * SS + qA)) * HID + h * HD + quad * 4;
    bf16* CpB = CpA + (size_t)64 * HID;
#pragma unroll
    for (int dn = 0; dn < 4; ++dn) {
      bf16x4 ovA, ovB;
#pragma unroll
      for (int r = 0; r < 4; ++r) {
        ovA[r] = (bf16)(oA[dn][r] * invA);
        ovB[r] = (bf16)(oB[dn][r] * invB);
      }
      *(bf16x4*)(CpA + dn * 16) = ovA;
      *(bf16x4*)(CpB + dn * 16) = ovB;
    }
  }
}

// ---------------- launch ----------------
extern "C" void kernel_launch(void* const* d_in, const int* in_sizes, int n_in,
                              void* d_out, int out_size, void* d_ws, size_t ws_size,
                              hipStream_t stream) {
  const float* hs = (const float*)d_in[0];
  const float* Wq = (const float*)d_in[2];
  const float* Wk = (const float*)d_in[3];
  const float* Wv = (const float*)d_in[4];
  const float* Wo = (const float*)d_in[5];

  char* ws = (char*)d_ws;
  bf16* A_b  = (bf16*)(ws);              // 16 MB ; reused as Ctx after QKV gemm
  bf16* Wq_b = (bf16*)(ws + 16777216);   // 8 MB
  bf16* Wk_b = (bf16*)(ws + 25165824);   // 2 MB
  bf16* Wv_b = (bf16*)(ws + 27262976);   // 2 MB
  bf16* Wo_b = (bf16*)(ws + 29360128);   // 8 MB
  bf16* Qb   = (bf16*)(ws + 37748736);   // 16 MB
  bf16* Kb   = (bf16*)(ws + 54525952);   // 4 MB
  bf16* Vt   = (bf16*)(ws + 58720256);   // 4 MB  (end: 62914560)
  bf16* Ctx  = A_b;

  cvt_all<<<18432, 256, 0, stream>>>(hs, Wq, Wk, Wv, Wo, A_b, Wq_b, Wk_b, Wv_b, Wo_b);
  gemm_qkv<<<dim3(MTOT / 256, 24), 512, 0, stream>>>(A_b, Wq_b, Wk_b, Wv_b, Qb, Kb, Vt);
  attn<<<dim3(8, BB * NH), 256, 0, stream>>>(Qb, Kb, Vt, Ctx);
  gemm_out<<<dim3(MTOT / 256, HID / 128), 512, 0, stream>>>(Ctx, Wo_b, (float*)d_out);
}

// Round 8
// 292.828 us; speedup vs baseline: 1.0177x; 1.0177x over previous
//
#include <hip/hip_runtime.h>
#include <math.h>

#define HID 2048
#define NH 32
#define NKV 8
#define HD 64
#define BB 2
#define SS 2048
#define MTOT (BB * SS) // 4096

typedef __bf16 bf16;
typedef __bf16 bf16x8 __attribute__((ext_vector_type(8)));
typedef __bf16 bf16x4 __attribute__((ext_vector_type(4)));
typedef float f32x4 __attribute__((ext_vector_type(4)));

#define MFMA16(a, b, c) __builtin_amdgcn_mfma_f32_16x16x32_bf16((a), (b), (c), 0, 0, 0)

__device__ __forceinline__ void load_lds16(const void* g, void* l) {
  __builtin_amdgcn_global_load_lds((const __attribute__((address_space(1))) void*)g,
                                   (__attribute__((address_space(3))) void*)l, 16, 0, 0);
}

#define FENCE() asm volatile("" ::: "memory")
// Tile-top sync: counted vmcnt (never 0 in main loop) + lgkmcnt(0) so this
// wave's ds_reads have COMPLETED before it enters the barrier (orders them
// against other waves' post-barrier global_load_lds writebacks), then barrier.
#define SYNC_VM(N) do { FENCE(); \
  asm volatile("s_waitcnt vmcnt(" #N ") lgkmcnt(0)" ::: "memory"); \
  __builtin_amdgcn_s_barrier(); FENCE(); } while (0)

// ---------------- fused fp32 -> bf16 convert: 8 elem/thread, 16B stores ----------------
// Ledger analysis (R0-R7) put the old 4-elem/8B-store version at ~65 us
// (~1.7 TB/s for 113 MB). 32B load + 16B store per thread, half the blocks.
// Segments in 2048-element blocks: hs 4096 | Wq 2048 | Wk 512 | Wv 512 | Wo 2048.
__global__ void cvt_all(const float* __restrict__ hs, const float* __restrict__ Wq,
                        const float* __restrict__ Wk, const float* __restrict__ Wv,
                        const float* __restrict__ Wo,
                        bf16* __restrict__ A_b, bf16* __restrict__ Wq_b,
                        bf16* __restrict__ Wk_b, bf16* __restrict__ Wv_b,
                        bf16* __restrict__ Wo_b) {
  int bid = blockIdx.x;
  const float* src;
  bf16* dst;
  if (bid < 4096)      { src = hs; dst = A_b; }
  else if (bid < 6144) { src = Wq; dst = Wq_b; bid -= 4096; }
  else if (bid < 6656) { src = Wk; dst = Wk_b; bid -= 6144; }
  else if (bid < 7168) { src = Wv; dst = Wv_b; bid -= 6656; }
  else                 { src = Wo; dst = Wo_b; bid -= 7168; }
  int i = (bid * 256 + threadIdx.x) * 8;
  float4 v0 = *(const float4*)(src + i);
  float4 v1 = *(const float4*)(src + i + 4);
  bf16x8 o;
  o[0] = (bf16)v0.x; o[1] = (bf16)v0.y; o[2] = (bf16)v0.z; o[3] = (bf16)v0.w;
  o[4] = (bf16)v1.x; o[5] = (bf16)v1.y; o[6] = (bf16)v1.z; o[7] = (bf16)v1.w;
  *(bf16x8*)(dst + i) = o;
}

// ---------------- BK=32 pipelined core (verified round 4/5): 256x128, 8 waves ----------------
// 72 KB -> 2 WG/CU (16 waves) -- the best measured waves/CU config for qkv.
__device__ __forceinline__ void gemm_core256x128(const char* Agc, const char* Bgc,
                                                 char* lds, f32x4 (&acc)[4][4]) {
  constexpr int ABYTES = 16384;     // A tile bytes (256 x 32 bf16)
  constexpr int BUFB = 24576;       // + B tile (128 x 32 bf16)
  constexpr int NT = HID / 32;      // 64 K-tiles

  const int tid = threadIdx.x;
  const int w = tid >> 6, lane = tid & 63;
  const int l16 = lane & 15, quad = lane >> 4;
  const int wr = w >> 1, wc = w & 1;
  const int wb = w * 1024;          // wave-uniform LDS staging base

  const int cu = (tid & 7) ^ ((tid >> 3) & 7);
  const int srcR0 = 2 * (tid >> 3) + (cu >> 2);   // 0..127
  const int srcC = (cu & 3) * 16;
  const char* gA = Agc + (size_t)srcR0 * (HID * 2) + srcC;
  const char* gB = Bgc + (size_t)srcR0 * (HID * 2) + srcC;

  const int acg16 = ((((l16 & 1) << 2) | quad) ^ ((l16 >> 1) & 7)) * 16;
  const int aoff = (wr * 32 + (l16 >> 1)) * 128 + acg16;
  const int boff = ABYTES + (wc * 32 + (l16 >> 1)) * 128 + acg16;

#pragma unroll
  for (int t0 = 0; t0 < 2; ++t0) {
    char* lb = lds + t0 * BUFB;
    load_lds16(gA + t0 * 64, lb + wb);
    load_lds16(gA + (size_t)128 * (HID * 2) + t0 * 64, lb + 8192 + wb);
    load_lds16(gB + t0 * 64, lb + ABYTES + wb);
  }

  char* cur = lds;
  char* stg = lds + 2 * BUFB;
  for (int kt = 0; kt < NT; ++kt) {
    SYNC_VM(3);
    const int ks = (kt + 2 < NT) ? (kt + 2) * 64 : (NT - 1) * 64;

    load_lds16(gA + ks, stg + wb);
    load_lds16(gA + (size_t)128 * (HID * 2) + ks, stg + 8192 + wb);
    load_lds16(gB + ks, stg + ABYTES + wb);
    FENCE();

    bf16x8 af[4], bfr[4];
#pragma unroll
    for (int ni = 0; ni < 4; ++ni)
      bfr[ni] = *(const bf16x8*)(cur + boff + ni * 1024);
#pragma unroll
    for (int mi = 0; mi < 4; ++mi)
      af[mi] = *(const bf16x8*)(cur + aoff + mi * 1024);
    __builtin_amdgcn_s_setprio(1);
#pragma unroll
    for (int mi = 0; mi < 4; ++mi)
#pragma unroll
      for (int ni = 0; ni < 4; ++ni)
        acc[mi][ni] = MFMA16(af[mi], bfr[ni], acc[mi][ni]);
    __builtin_amdgcn_s_setprio(0);

    cur = (cur == lds + 2 * BUFB) ? lds : cur + BUFB;
    stg = (stg == lds + 2 * BUFB) ? lds : stg + BUFB;
  }
  asm volatile("s_waitcnt vmcnt(0)" ::: "memory");
}

// ---------------- BK=64 single-phase core (verified round 6; best at full fill) ----------------
// 3 rotating 48 KB buffers (144 KB -> 1 WG/CU), SYNC_VM(6) at step top, one
// barrier per K-step, 32 MFMA/wave/step. R6 measured per-round rate: 54.4 us
// for a 256-block full-fill launch. (The round-7 2-phase variant regressed
// ~1.7x -- m196-style coarse split without fine interleave. Do not re-add.)
__device__ __forceinline__ void gemm_core_k64(const char* Agc, const char* Bgc,
                                              char* lds, f32x4 (&acc)[4][4]) {
  constexpr int ABYTES = 32768;   // A tile: 256 rows x 64 cols bf16
  constexpr int BUFB = 49152;     // + B tile: 128 rows x 64 cols bf16
  constexpr int NT = HID / 64;    // 32 K-steps

  const int tid = threadIdx.x;
  const int w = tid >> 6, lane = tid & 63;
  const int l16 = lane & 15, quad = lane >> 4;
  const int wr = w >> 1, wc = w & 1;
  const int wb = w * 1024;        // wave-uniform LDS staging base

  // staging: wave w, load j -> row = w*8 + j*64 + (lane>>3),
  // logical chunk = (lane&7) ^ ((lane>>3)&7); inverse swizzle on global src.
  const int cu = (lane & 7) ^ ((lane >> 3) & 7);
  const char* gA = Agc + (size_t)(w * 8 + (lane >> 3)) * 4096 + cu * 16;
  const char* gB = Bgc + (size_t)(w * 8 + (lane >> 3)) * 4096 + cu * 16;

  // ds_read: row r chunk c at (c ^ (r&7))*16
  const int aswz = l16 & 7;
  const int a_k0 = ((0 + quad) ^ aswz) * 16;   // ks = 0
  const int a_k1 = ((4 + quad) ^ aswz) * 16;   // ks = 1
  const int arow = (wr * 64 + l16) * 128;
  const int brow = (wc * 64 + l16) * 128;

  // prologue: stage K-steps 0 and 1 (6 loads per wave per K-step: 4 A + 2 B)
#pragma unroll
  for (int t0 = 0; t0 < 2; ++t0) {
    char* lb = lds + t0 * BUFB;
#pragma unroll
    for (int j = 0; j < 4; ++j)
      load_lds16(gA + (size_t)j * (64 * 4096) + t0 * 128, lb + wb + j * 8192);
#pragma unroll
    for (int j = 0; j < 2; ++j)
      load_lds16(gB + (size_t)j * (64 * 4096) + t0 * 128, lb + ABYTES + wb + j * 8192);
  }

  char* cur = lds;
  char* stg = lds + 2 * BUFB;
  for (int kt = 0; kt < NT; ++kt) {
    SYNC_VM(6);
    const int ks = (kt + 2 < NT) ? (kt + 2) : (NT - 1);
    const size_t ko = (size_t)ks * 128;

#pragma unroll
    for (int j = 0; j < 4; ++j)
      load_lds16(gA + (size_t)j * (64 * 4096) + ko, stg + wb + j * 8192);
#pragma unroll
    for (int j = 0; j < 2; ++j)
      load_lds16(gB + (size_t)j * (64 * 4096) + ko, stg + ABYTES + wb + j * 8192);
    FENCE();

    const char* Ac = cur;
    const char* Bc = cur + ABYTES;
    bf16x8 af0[4], af1[4], bf0[4], bf1[4];
#pragma unroll
    for (int ni = 0; ni < 4; ++ni) {
      bf0[ni] = *(const bf16x8*)(Bc + brow + ni * 2048 + a_k0);
      bf1[ni] = *(const bf16x8*)(Bc + brow + ni * 2048 + a_k1);
    }
#pragma unroll
    for (int mi = 0; mi < 4; ++mi) {
      af0[mi] = *(const bf16x8*)(Ac + arow + mi * 2048 + a_k0);
      af1[mi] = *(const bf16x8*)(Ac + arow + mi * 2048 + a_k1);
    }
    __builtin_amdgcn_s_setprio(1);
#pragma unroll
    for (int mi = 0; mi < 4; ++mi)
#pragma unroll
      for (int ni = 0; ni < 4; ++ni) {
        acc[mi][ni] = MFMA16(af0[mi], bf0[ni], acc[mi][ni]);
        acc[mi][ni] = MFMA16(af1[mi], bf1[ni], acc[mi][ni]);
      }
    __builtin_amdgcn_s_setprio(0);

    cur = (cur == lds + 2 * BUFB) ? lds : cur + BUFB;
    stg = (stg == lds + 2 * BUFB) ? lds : stg + BUFB;
  }
  asm volatile("s_waitcnt vmcnt(0)" ::: "memory");
}

// ---------------- fused QKV projection + RoPE epilogue (verified R5/R7) ----------------
#define QSCALE 0.1803368801f
#define L2B 0.4152410118f  // log2(10000)/32
__global__ __launch_bounds__(512, 4) void gemm_qkv(const bf16* __restrict__ A,
                                                   const bf16* __restrict__ Wq,
                                                   const bf16* __restrict__ Wk,
                                                   const bf16* __restrict__ Wv,
                                                   bf16* __restrict__ Qb,
                                                   bf16* __restrict__ Kb,
                                                   bf16* __restrict__ Vt) {
  __shared__ __align__(16) char lds[3 * 24576];  // 72 KB -> 2 WG/CU (16 waves)
  const int tileM = blockIdx.x * 256;
  const int n0 = blockIdx.y * 128;
  const bf16* Wp;
  int mode;
  if (n0 < HID) { Wp = Wq + (size_t)n0 * HID; mode = 0; }
  else if (n0 < HID + 512) { Wp = Wk + (size_t)(n0 - HID) * HID; mode = 1; }
  else { Wp = Wv + (size_t)(n0 - HID - 512) * HID; mode = 2; }

  f32x4 acc[4][4];
#pragma unroll
  for (int i = 0; i < 4; ++i)
#pragma unroll
    for (int j = 0; j < 4; ++j) acc[i][j] = (f32x4){0.f, 0.f, 0.f, 0.f};

  gemm_core256x128((const char*)(A + (size_t)tileM * HID), (const char*)Wp, lds, acc);

  const int tid = threadIdx.x;
  const int w = tid >> 6, lane = tid & 63;
  const int l16 = lane & 15, quad = lane >> 4;
  const int wr = w >> 1, wc = w & 1;
  const int mbase = tileM + wr * 64;
  const int cb = n0 + wc * 64;  // 64-aligned -> wave col span = one head

  if (mode == 2) {
    // V: transposed layout [b,kvh,d,s]
#pragma unroll
    for (int mi = 0; mi < 4; ++mi)
#pragma unroll
      for (int ni = 0; ni < 4; ++ni)
#pragma unroll
        for (int r = 0; r < 4; ++r) {
          int grow = mbase + mi * 16 + quad * 4 + r;
          int b = grow >> 11, spos = grow & (SS - 1);
          int nv = cb + ni * 16 + l16 - (HID + 512);
          Vt[(((size_t)(b * NKV + (nv >> 6))) * HD + (nv & 63)) * SS + spos] =
              (bf16)acc[mi][ni][r];
        }
  } else {
    // Q or K: RoPE in fp32 regs; pairs (ni=0,ni=2) at freq l16, (1,3) at l16+16.
    const float inv0 = __builtin_amdgcn_exp2f(-(float)l16 * L2B);
    const float inv1 = __builtin_amdgcn_exp2f(-(float)(l16 + 16) * L2B);
#pragma unroll
    for (int mi = 0; mi < 4; ++mi) {
#pragma unroll
      for (int r = 0; r < 4; ++r) {
        int grow = mbase + mi * 16 + quad * 4 + r;
        int b = grow >> 11, spos = grow & (SS - 1);
        float sn0, cs0, sn1, cs1;
        sincosf((float)spos * inv0, &sn0, &cs0);
        sincosf((float)spos * inv1, &sn1, &cs1);
        float a0 = acc[mi][0][r], a1 = acc[mi][1][r];
        float a2 = acc[mi][2][r], a3 = acc[mi][3][r];
        float o0 = a0 * cs0 - a2 * sn0;
        float o2 = a2 * cs0 + a0 * sn0;
        float o1 = a1 * cs1 - a3 * sn1;
        float o3 = a3 * cs1 + a1 * sn1;
        if (mode == 0) {
          bf16* qp = Qb + (size_t)grow * HID + cb + l16;
          qp[0]  = (bf16)(o0 * QSCALE);
          qp[16] = (bf16)(o1 * QSCALE);
          qp[32] = (bf16)(o2 * QSCALE);
          qp[48] = (bf16)(o3 * QSCALE);
        } else {
          int kvh = (cb - HID) >> 6;
          bf16* kp = Kb + ((size_t)(b * NKV + kvh) * SS + spos) * HD + l16;
          kp[0]  = (bf16)o0;
          kp[16] = (bf16)o1;
          kp[32] = (bf16)o2;
          kp[48] = (bf16)o3;
        }
      }
    }
  }
}

// ---------------- output projection (grid 16x16 = 256 blocks = 1/CU, BK=64 single-phase) ----------------
__global__ __launch_bounds__(512, 2) void gemm_out(const bf16* __restrict__ A,
                                                   const bf16* __restrict__ Wo,
                                                   float* __restrict__ out) {
  __shared__ __align__(16) char lds[3 * 49152];  // 144 KB -> 1 WG/CU
  const int tileM = blockIdx.x * 256;
  const int n0 = blockIdx.y * 128;
  f32x4 acc[4][4];
#pragma unroll
  for (int i = 0; i < 4; ++i)
#pragma unroll
    for (int j = 0; j < 4; ++j) acc[i][j] = (f32x4){0.f, 0.f, 0.f, 0.f};

  gemm_core_k64((const char*)(A + (size_t)tileM * HID),
                (const char*)(Wo + (size_t)n0 * HID), lds, acc);

  const int tid = threadIdx.x;
  const int w = tid >> 6, lane = tid & 63;
  const int l16 = lane & 15, quad = lane >> 4;
  const int wr = w >> 1, wc = w & 1;
#pragma unroll
  for (int mi = 0; mi < 4; ++mi)
#pragma unroll
    for (int ni = 0; ni < 4; ++ni)
#pragma unroll
      for (int r = 0; r < 4; ++r) {
        int grow = tileM + wr * 64 + mi * 16 + quad * 4 + r;
        int gcol = n0 + wc * 64 + ni * 16 + l16;
        out[(size_t)grow * HID + gcol] = acc[mi][ni][r];
      }
}

// ---------------- flash attention v6: 128 q-rows per block (verified round 5) ----------------
#define PSTR 72
__global__ __launch_bounds__(256, 3) void attn(const bf16* __restrict__ Qb,
                                               const bf16* __restrict__ Kb,
                                               const bf16* __restrict__ Vt,
                                               bf16* __restrict__ Ctx) {
  __shared__ bf16 Ktile[2][64 * 64];
  __shared__ bf16 Vtile[2][64 * 64];
  __shared__ bf16 Pbuf[4][32 * PSTR];   // per wave: rows 0-15 = A, 16-31 = B
  const int tid = threadIdx.x;
  const int w = tid >> 6, lane = tid & 63;
  const int l16 = lane & 15, quad = lane >> 4;
  const int bh = blockIdx.y, b = bh >> 5, h = bh & 31, kvh = h >> 2;
  bf16* Pw = &Pbuf[w][0];
  const char* Kslice = (const char*)(Kb + ((size_t)(b * NKV + kvh)) * SS * HD);
  const char* Vslice = (const char*)(Vt + ((size_t)(b * NKV + kvh)) * HD * SS);
  const int qrel = w * 16 + l16;        // 0..63 within each 64-row subtile

  const int srow = (lane >> 3) & 7;
  const int pchunk = ((lane & 7) ^ srow) << 4;
  const int so = ((quad ^ (l16 & 7)) << 4);
  const int so2 = so ^ 64;

  const int xA = (int)blockIdx.x;       // 0..7

  int cur = 0;
  {
#pragma unroll
    for (int i = 0; i < 2; ++i) {
      const int r = w * 16 + i * 8 + srow;
      load_lds16(Kslice + (size_t)r * 128 + pchunk,
                 (char*)Ktile[0] + (w * 16 + i * 8) * 128);
      load_lds16(Vslice + (size_t)r * 4096 + pchunk,
                 (char*)Vtile[0] + (w * 16 + i * 8) * 128);
    }
  }

  for (int t = 0; t < 2; ++t) {
    const int X = t ? (15 - xA) : xA;   // 128-row superblock index
    const int qA = X * 128 + qrel;
    const int ktmax = 2 * X + 1;        // last kv tile (64 keys each)

    const bf16* QpA = Qb + ((size_t)(b * SS + qA)) * HID + h * HD + quad * 8;
    bf16x8 qa0 = *(const bf16x8*)QpA;
    bf16x8 qa1 = *(const bf16x8*)(QpA + 32);
    const bf16* QpB = QpA + (size_t)64 * HID;
    bf16x8 qbB0 = *(const bf16x8*)QpB;
    bf16x8 qbB1 = *(const bf16x8*)(QpB + 32);

    float lA = 0.f, lB = 0.f;
    f32x4 oA[4], oB[4];
#pragma unroll
    for (int d = 0; d < 4; ++d) {
      oA[d] = (f32x4){0.f, 0.f, 0.f, 0.f};
      oB[d] = (f32x4){0.f, 0.f, 0.f, 0.f};
    }

    for (int kt = 0; kt <= ktmax; ++kt) {
      __syncthreads();   // cur tile ready (staged a full compute phase ago)

      const bool have_next = (kt < ktmax) || (t == 0);
      if (have_next) {
        const int nkb = (kt < ktmax) ? (kt + 1) * 64 : 0;  // last: tile 0 for pass 1
        const int nb = cur ^ 1;
#pragma unroll
        for (int i = 0; i < 2; ++i) {
          const int r = w * 16 + i * 8 + srow;
          load_lds16(Kslice + (size_t)(nkb + r) * 128 + pchunk,
                     (char*)Ktile[nb] + (w * 16 + i * 8) * 128);
          load_lds16(Vslice + (size_t)r * 4096 + (size_t)nkb * 2 + pchunk,
                     (char*)Vtile[nb] + (w * 16 + i * 8) * 128);
        }
      }

      const char* Kc = (const char*)Ktile[cur] + l16 * 128;
      const char* Vc = (const char*)Vtile[cur] + l16 * 128;
      const bool skipA = (kt == ktmax);       // A fully masked on last tile
      const bool diagA = (kt == ktmax - 1);   // kt == 2X
      const bool diagB = (kt == ktmax);       // kt == 2X+1

#pragma unroll
      for (int nt = 0; nt < 4; ++nt) {
        bf16x8 kf0 = *(const bf16x8*)(Kc + nt * 2048 + so);
        bf16x8 kf1 = *(const bf16x8*)(Kc + nt * 2048 + so2);
        const int krel = nt * 16 + quad * 4;

        bf16x4 pkA;
        if (skipA) {
          pkA[0] = (bf16)0.f; pkA[1] = (bf16)0.f;
          pkA[2] = (bf16)0.f; pkA[3] = (bf16)0.f;
        } else {
          f32x4 s = {0.f, 0.f, 0.f, 0.f};
          s = MFMA16(kf0, qa0, s);   // S^T: row = key, col = q (l16)
          s = MFMA16(kf1, qa1, s);
          if (diagA) {
#pragma unroll
            for (int r = 0; r < 4; ++r) {
              float p = (krel + r > qrel) ? 0.f : __builtin_amdgcn_exp2f(s[r]);
              lA += p;
              pkA[r] = (bf16)p;
            }
          } else {
#pragma unroll
            for (int r = 0; r < 4; ++r) {
              float p = __builtin_amdgcn_exp2f(s[r]);
              lA += p;
              pkA[r] = (bf16)p;
            }
          }
        }
        *(bf16x4*)&Pw[l16 * PSTR + krel] = pkA;

        f32x4 sB = {0.f, 0.f, 0.f, 0.f};
        sB = MFMA16(kf0, qbB0, sB);
        sB = MFMA16(kf1, qbB1, sB);
        bf16x4 pkB;
        if (diagB) {
#pragma unroll
          for (int r = 0; r < 4; ++r) {
            float p = (krel + r > qrel) ? 0.f : __builtin_amdgcn_exp2f(sB[r]);
            lB += p;
            pkB[r] = (bf16)p;
          }
        } else {
#pragma unroll
          for (int r = 0; r < 4; ++r) {
            float p = __builtin_amdgcn_exp2f(sB[r]);
            lB += p;
            pkB[r] = (bf16)p;
          }
        }
        *(bf16x4*)&Pw[(16 + l16) * PSTR + krel] = pkB;
      }

      bf16x8 pA0 = *(const bf16x8*)&Pw[l16 * PSTR + quad * 8];
      bf16x8 pA1 = *(const bf16x8*)&Pw[l16 * PSTR + 32 + quad * 8];
      bf16x8 pB0 = *(const bf16x8*)&Pw[(16 + l16) * PSTR + quad * 8];
      bf16x8 pB1 = *(const bf16x8*)&Pw[(16 + l16) * PSTR + 32 + quad * 8];
#pragma unroll
      for (int dn = 0; dn < 4; ++dn) {
        bf16x8 v0 = *(const bf16x8*)(Vc + dn * 2048 + so);
        bf16x8 v1 = *(const bf16x8*)(Vc + dn * 2048 + so2);
        oA[dn] = MFMA16(v0, pA0, oA[dn]);  // O^T: row = d, col = q
        oA[dn] = MFMA16(v1, pA1, oA[dn]);
        oB[dn] = MFMA16(v0, pB0, oB[dn]);
        oB[dn] = MFMA16(v1, pB1, oB[dn]);
      }
      cur ^= 1;
    }

    lA += __shfl_xor(lA, 16);
    lA += __shfl_xor(lA, 32);
    lB += __shfl_xor(lB, 16);
    lB += __shfl_xor(lB, 32);
    const float invA = 1.0f / lA;
    const float invB = 1.0f / lB;
    bf16* CpA = Ctx + ((size_t)(b * SS + qA)) * HID + h * HD + quad * 4;
    bf16* CpB = CpA + (size_t)64 * HID;
#pragma unroll
    for (int dn = 0; dn < 4; ++dn) {
      bf16x4 ovA, ovB;
#pragma unroll
      for (int r = 0; r < 4; ++r) {
        ovA[r] = (bf16)(oA[dn][r] * invA);
        ovB[r] = (bf16)(oB[dn][r] * invB);
      }
      *(bf16x4*)(CpA + dn * 16) = ovA;
      *(bf16x4*)(CpB + dn * 16) = ovB;
    }
  }
}

// ---------------- launch ----------------
extern "C" void kernel_launch(void* const* d_in, const int* in_sizes, int n_in,
                              void* d_out, int out_size, void* d_ws, size_t ws_size,
                              hipStream_t stream) {
  const float* hs = (const float*)d_in[0];
  const float* Wq = (const float*)d_in[2];
  const float* Wk = (const float*)d_in[3];
  const float* Wv = (const float*)d_in[4];
  const float* Wo = (const float*)d_in[5];

  char* ws = (char*)d_ws;
  bf16* A_b  = (bf16*)(ws);              // 16 MB ; reused as Ctx after QKV gemm
  bf16* Wq_b = (bf16*)(ws + 16777216);   // 8 MB
  bf16* Wk_b = (bf16*)(ws + 25165824);   // 2 MB
  bf16* Wv_b = (bf16*)(ws + 27262976);   // 2 MB
  bf16* Wo_b = (bf16*)(ws + 29360128);   // 8 MB
  bf16* Qb   = (bf16*)(ws + 37748736);   // 16 MB
  bf16* Kb   = (bf16*)(ws + 54525952);   // 4 MB
  bf16* Vt   = (bf16*)(ws + 58720256);   // 4 MB  (end: 62914560)
  bf16* Ctx  = A_b;

  cvt_all<<<9216, 256, 0, stream>>>(hs, Wq, Wk, Wv, Wo, A_b, Wq_b, Wk_b, Wv_b, Wo_b);
  gemm_qkv<<<dim3(MTOT / 256, 24), 512, 0, stream>>>(A_b, Wq_b, Wk_b, Wv_b, Qb, Kb, Vt);
  attn<<<dim3(8, BB * NH), 256, 0, stream>>>(Qb, Kb, Vt, Ctx);
  gemm_out<<<dim3(MTOT / 256, HID / 128), 512, 0, stream>>>(Ctx, Wo_b, (float*)d_out);
}

// Round 9
// 292.159 us; speedup vs baseline: 1.0200x; 1.0023x over previous
//
#include <hip/hip_runtime.h>
#include <math.h>

#define HID 2048
#define NH 32
#define NKV 8
#define HD 64
#define BB 2
#define SS 2048
#define MTOT (BB * SS) // 4096

typedef __bf16 bf16;
typedef __bf16 bf16x8 __attribute__((ext_vector_type(8)));
typedef __bf16 bf16x4 __attribute__((ext_vector_type(4)));
typedef float f32x4 __attribute__((ext_vector_type(4)));

#define MFMA16(a, b, c) __builtin_amdgcn_mfma_f32_16x16x32_bf16((a), (b), (c), 0, 0, 0)

__device__ __forceinline__ void load_lds16(const void* g, void* l) {
  __builtin_amdgcn_global_load_lds((const __attribute__((address_space(1))) void*)g,
                                   (__attribute__((address_space(3))) void*)l, 16, 0, 0);
}

#define FENCE() asm volatile("" ::: "memory")
// Tile-top sync: counted vmcnt (never 0 in main loop) + lgkmcnt(0) so this
// wave's ds_reads have COMPLETED before it enters the barrier (orders them
// against other waves' post-barrier global_load_lds writebacks), then barrier.
#define SYNC_VM(N) do { FENCE(); \
  asm volatile("s_waitcnt vmcnt(" #N ") lgkmcnt(0)" ::: "memory"); \
  __builtin_amdgcn_s_barrier(); FENCE(); } while (0)

// ---------------- fused fp32 -> bf16 convert, grid-stride (G11 recipe) ----------------
// Ledger (R6 vs R8 subtraction): single-shot 18432-WG version ran at only
// ~1.7 TB/s (WG-turnover-bound, one load per thread, no ILP); the R8 8-elem
// variant was WORSE (+34 us, stride-32B lanes = 2x line touches). This one
// keeps the verified R0 addressing (contiguous 16B/lane load, 8B/lane store)
// and adds a 9-deep grid-stride loop: 2048 blocks, 9 chunks each -> per-wave
// MLP and 9x fewer dispatches. Chunk map (1024 floats each):
// hs 8192 | Wq 4096 | Wk 1024 | Wv 1024 | Wo 4096  (total 18432).
#define CVT_CHUNKS 18432
#define CVT_BLOCKS 2048
__global__ void cvt_all(const float* __restrict__ hs, const float* __restrict__ Wq,
                        const float* __restrict__ Wk, const float* __restrict__ Wv,
                        const float* __restrict__ Wo,
                        bf16* __restrict__ A_b, bf16* __restrict__ Wq_b,
                        bf16* __restrict__ Wk_b, bf16* __restrict__ Wv_b,
                        bf16* __restrict__ Wo_b) {
  const int tid = threadIdx.x;
#pragma unroll 1
  for (int c = blockIdx.x; c < CVT_CHUNKS; c += CVT_BLOCKS) {
    int cc = c;
    const float* src;
    bf16* dst;
    if (cc < 8192)       { src = hs; dst = A_b; }
    else if (cc < 12288) { src = Wq; dst = Wq_b; cc -= 8192; }
    else if (cc < 13312) { src = Wk; dst = Wk_b; cc -= 12288; }
    else if (cc < 14336) { src = Wv; dst = Wv_b; cc -= 13312; }
    else                 { src = Wo; dst = Wo_b; cc -= 14336; }
    int i = (cc * 256 + tid) * 4;
    float4 v = *(const float4*)(src + i);
    bf16x4 o;
    o[0] = (bf16)v.x; o[1] = (bf16)v.y; o[2] = (bf16)v.z; o[3] = (bf16)v.w;
    *(bf16x4*)(dst + i) = o;
  }
}

// ---------------- BK=32 pipelined core (verified round 4/5): 256x128, 8 waves ----------------
// 72 KB -> 2 WG/CU (16 waves) -- the best measured waves/CU config for qkv.
__device__ __forceinline__ void gemm_core256x128(const char* Agc, const char* Bgc,
                                                 char* lds, f32x4 (&acc)[4][4]) {
  constexpr int ABYTES = 16384;     // A tile bytes (256 x 32 bf16)
  constexpr int BUFB = 24576;       // + B tile (128 x 32 bf16)
  constexpr int NT = HID / 32;      // 64 K-tiles

  const int tid = threadIdx.x;
  const int w = tid >> 6, lane = tid & 63;
  const int l16 = lane & 15, quad = lane >> 4;
  const int wr = w >> 1, wc = w & 1;
  const int wb = w * 1024;          // wave-uniform LDS staging base

  const int cu = (tid & 7) ^ ((tid >> 3) & 7);
  const int srcR0 = 2 * (tid >> 3) + (cu >> 2);   // 0..127
  const int srcC = (cu & 3) * 16;
  const char* gA = Agc + (size_t)srcR0 * (HID * 2) + srcC;
  const char* gB = Bgc + (size_t)srcR0 * (HID * 2) + srcC;

  const int acg16 = ((((l16 & 1) << 2) | quad) ^ ((l16 >> 1) & 7)) * 16;
  const int aoff = (wr * 32 + (l16 >> 1)) * 128 + acg16;
  const int boff = ABYTES + (wc * 32 + (l16 >> 1)) * 128 + acg16;

#pragma unroll
  for (int t0 = 0; t0 < 2; ++t0) {
    char* lb = lds + t0 * BUFB;
    load_lds16(gA + t0 * 64, lb + wb);
    load_lds16(gA + (size_t)128 * (HID * 2) + t0 * 64, lb + 8192 + wb);
    load_lds16(gB + t0 * 64, lb + ABYTES + wb);
  }

  char* cur = lds;
  char* stg = lds + 2 * BUFB;
  for (int kt = 0; kt < NT; ++kt) {
    SYNC_VM(3);
    const int ks = (kt + 2 < NT) ? (kt + 2) * 64 : (NT - 1) * 64;

    load_lds16(gA + ks, stg + wb);
    load_lds16(gA + (size_t)128 * (HID * 2) + ks, stg + 8192 + wb);
    load_lds16(gB + ks, stg + ABYTES + wb);
    FENCE();

    bf16x8 af[4], bfr[4];
#pragma unroll
    for (int ni = 0; ni < 4; ++ni)
      bfr[ni] = *(const bf16x8*)(cur + boff + ni * 1024);
#pragma unroll
    for (int mi = 0; mi < 4; ++mi)
      af[mi] = *(const bf16x8*)(cur + aoff + mi * 1024);
    __builtin_amdgcn_s_setprio(1);
#pragma unroll
    for (int mi = 0; mi < 4; ++mi)
#pragma unroll
      for (int ni = 0; ni < 4; ++ni)
        acc[mi][ni] = MFMA16(af[mi], bfr[ni], acc[mi][ni]);
    __builtin_amdgcn_s_setprio(0);

    cur = (cur == lds + 2 * BUFB) ? lds : cur + BUFB;
    stg = (stg == lds + 2 * BUFB) ? lds : stg + BUFB;
  }
  asm volatile("s_waitcnt vmcnt(0)" ::: "memory");
}

// ---------------- BK=64 single-phase core (verified round 6; best at full fill) ----------------
// 3 rotating 48 KB buffers (144 KB -> 1 WG/CU), SYNC_VM(6) at step top, one
// barrier per K-step, 32 MFMA/wave/step. (The round-7 2-phase variant
// regressed ~1.7x -- coarse split without fine interleave. Do not re-add.)
__device__ __forceinline__ void gemm_core_k64(const char* Agc, const char* Bgc,
                                              char* lds, f32x4 (&acc)[4][4]) {
  constexpr int ABYTES = 32768;   // A tile: 256 rows x 64 cols bf16
  constexpr int BUFB = 49152;     // + B tile: 128 rows x 64 cols bf16
  constexpr int NT = HID / 64;    // 32 K-steps

  const int tid = threadIdx.x;
  const int w = tid >> 6, lane = tid & 63;
  const int l16 = lane & 15, quad = lane >> 4;
  const int wr = w >> 1, wc = w & 1;
  const int wb = w * 1024;        // wave-uniform LDS staging base

  // staging: wave w, load j -> row = w*8 + j*64 + (lane>>3),
  // logical chunk = (lane&7) ^ ((lane>>3)&7); inverse swizzle on global src.
  const int cu = (lane & 7) ^ ((lane >> 3) & 7);
  const char* gA = Agc + (size_t)(w * 8 + (lane >> 3)) * 4096 + cu * 16;
  const char* gB = Bgc + (size_t)(w * 8 + (lane >> 3)) * 4096 + cu * 16;

  // ds_read: row r chunk c at (c ^ (r&7))*16
  const int aswz = l16 & 7;
  const int a_k0 = ((0 + quad) ^ aswz) * 16;   // ks = 0
  const int a_k1 = ((4 + quad) ^ aswz) * 16;   // ks = 1
  const int arow = (wr * 64 + l16) * 128;
  const int brow = (wc * 64 + l16) * 128;

  // prologue: stage K-steps 0 and 1 (6 loads per wave per K-step: 4 A + 2 B)
#pragma unroll
  for (int t0 = 0; t0 < 2; ++t0) {
    char* lb = lds + t0 * BUFB;
#pragma unroll
    for (int j = 0; j < 4; ++j)
      load_lds16(gA + (size_t)j * (64 * 4096) + t0 * 128, lb + wb + j * 8192);
#pragma unroll
    for (int j = 0; j < 2; ++j)
      load_lds16(gB + (size_t)j * (64 * 4096) + t0 * 128, lb + ABYTES + wb + j * 8192);
  }

  char* cur = lds;
  char* stg = lds + 2 * BUFB;
  for (int kt = 0; kt < NT; ++kt) {
    SYNC_VM(6);
    const int ks = (kt + 2 < NT) ? (kt + 2) : (NT - 1);
    const size_t ko = (size_t)ks * 128;

#pragma unroll
    for (int j = 0; j < 4; ++j)
      load_lds16(gA + (size_t)j * (64 * 4096) + ko, stg + wb + j * 8192);
#pragma unroll
    for (int j = 0; j < 2; ++j)
      load_lds16(gB + (size_t)j * (64 * 4096) + ko, stg + ABYTES + wb + j * 8192);
    FENCE();

    const char* Ac = cur;
    const char* Bc = cur + ABYTES;
    bf16x8 af0[4], af1[4], bf0[4], bf1[4];
#pragma unroll
    for (int ni = 0; ni < 4; ++ni) {
      bf0[ni] = *(const bf16x8*)(Bc + brow + ni * 2048 + a_k0);
      bf1[ni] = *(const bf16x8*)(Bc + brow + ni * 2048 + a_k1);
    }
#pragma unroll
    for (int mi = 0; mi < 4; ++mi) {
      af0[mi] = *(const bf16x8*)(Ac + arow + mi * 2048 + a_k0);
      af1[mi] = *(const bf16x8*)(Ac + arow + mi * 2048 + a_k1);
    }
    __builtin_amdgcn_s_setprio(1);
#pragma unroll
    for (int mi = 0; mi < 4; ++mi)
#pragma unroll
      for (int ni = 0; ni < 4; ++ni) {
        acc[mi][ni] = MFMA16(af0[mi], bf0[ni], acc[mi][ni]);
        acc[mi][ni] = MFMA16(af1[mi], bf1[ni], acc[mi][ni]);
      }
    __builtin_amdgcn_s_setprio(0);

    cur = (cur == lds + 2 * BUFB) ? lds : cur + BUFB;
    stg = (stg == lds + 2 * BUFB) ? lds : stg + BUFB;
  }
  asm volatile("s_waitcnt vmcnt(0)" ::: "memory");
}

// ---------------- fused QKV projection + RoPE epilogue (verified R5/R7) ----------------
#define QSCALE 0.1803368801f
#define L2B 0.4152410118f  // log2(10000)/32
__global__ __launch_bounds__(512, 4) void gemm_qkv(const bf16* __restrict__ A,
                                                   const bf16* __restrict__ Wq,
                                                   const bf16* __restrict__ Wk,
                                                   const bf16* __restrict__ Wv,
                                                   bf16* __restrict__ Qb,
                                                   bf16* __restrict__ Kb,
                                                   bf16* __restrict__ Vt) {
  __shared__ __align__(16) char lds[3 * 24576];  // 72 KB -> 2 WG/CU (16 waves)
  const int tileM = blockIdx.x * 256;
  const int n0 = blockIdx.y * 128;
  const bf16* Wp;
  int mode;
  if (n0 < HID) { Wp = Wq + (size_t)n0 * HID; mode = 0; }
  else if (n0 < HID + 512) { Wp = Wk + (size_t)(n0 - HID) * HID; mode = 1; }
  else { Wp = Wv + (size_t)(n0 - HID - 512) * HID; mode = 2; }

  f32x4 acc[4][4];
#pragma unroll
  for (int i = 0; i < 4; ++i)
#pragma unroll
    for (int j = 0; j < 4; ++j) acc[i][j] = (f32x4){0.f, 0.f, 0.f, 0.f};

  gemm_core256x128((const char*)(A + (size_t)tileM * HID), (const char*)Wp, lds, acc);

  const int tid = threadIdx.x;
  const int w = tid >> 6, lane = tid & 63;
  const int l16 = lane & 15, quad = lane >> 4;
  const int wr = w >> 1, wc = w & 1;
  const int mbase = tileM + wr * 64;
  const int cb = n0 + wc * 64;  // 64-aligned -> wave col span = one head

  if (mode == 2) {
    // V: transposed layout [b,kvh,d,s]
#pragma unroll
    for (int mi = 0; mi < 4; ++mi)
#pragma unroll
      for (int ni = 0; ni < 4; ++ni)
#pragma unroll
        for (int r = 0; r < 4; ++r) {
          int grow = mbase + mi * 16 + quad * 4 + r;
          int b = grow >> 11, spos = grow & (SS - 1);
          int nv = cb + ni * 16 + l16 - (HID + 512);
          Vt[(((size_t)(b * NKV + (nv >> 6))) * HD + (nv & 63)) * SS + spos] =
              (bf16)acc[mi][ni][r];
        }
  } else {
    // Q or K: RoPE in fp32 regs; pairs (ni=0,ni=2) at freq l16, (1,3) at l16+16.
    const float inv0 = __builtin_amdgcn_exp2f(-(float)l16 * L2B);
    const float inv1 = __builtin_amdgcn_exp2f(-(float)(l16 + 16) * L2B);
#pragma unroll
    for (int mi = 0; mi < 4; ++mi) {
#pragma unroll
      for (int r = 0; r < 4; ++r) {
        int grow = mbase + mi * 16 + quad * 4 + r;
        int b = grow >> 11, spos = grow & (SS - 1);
        float sn0, cs0, sn1, cs1;
        sincosf((float)spos * inv0, &sn0, &cs0);
        sincosf((float)spos * inv1, &sn1, &cs1);
        float a0 = acc[mi][0][r], a1 = acc[mi][1][r];
        float a2 = acc[mi][2][r], a3 = acc[mi][3][r];
        float o0 = a0 * cs0 - a2 * sn0;
        float o2 = a2 * cs0 + a0 * sn0;
        float o1 = a1 * cs1 - a3 * sn1;
        float o3 = a3 * cs1 + a1 * sn1;
        if (mode == 0) {
          bf16* qp = Qb + (size_t)grow * HID + cb + l16;
          qp[0]  = (bf16)(o0 * QSCALE);
          qp[16] = (bf16)(o1 * QSCALE);
          qp[32] = (bf16)(o2 * QSCALE);
          qp[48] = (bf16)(o3 * QSCALE);
        } else {
          int kvh = (cb - HID) >> 6;
          bf16* kp = Kb + ((size_t)(b * NKV + kvh) * SS + spos) * HD + l16;
          kp[0]  = (bf16)o0;
          kp[16] = (bf16)o1;
          kp[32] = (bf16)o2;
          kp[48] = (bf16)o3;
        }
      }
    }
  }
}

// ---------------- output projection (grid 16x16 = 256 blocks = 1/CU, BK=64 single-phase) ----------------
__global__ __launch_bounds__(512, 2) void gemm_out(const bf16* __restrict__ A,
                                                   const bf16* __restrict__ Wo,
                                                   float* __restrict__ out) {
  __shared__ __align__(16) char lds[3 * 49152];  // 144 KB -> 1 WG/CU
  const int tileM = blockIdx.x * 256;
  const int n0 = blockIdx.y * 128;
  f32x4 acc[4][4];
#pragma unroll
  for (int i = 0; i < 4; ++i)
#pragma unroll
    for (int j = 0; j < 4; ++j) acc[i][j] = (f32x4){0.f, 0.f, 0.f, 0.f};

  gemm_core_k64((const char*)(A + (size_t)tileM * HID),
                (const char*)(Wo + (size_t)n0 * HID), lds, acc);

  const int tid = threadIdx.x;
  const int w = tid >> 6, lane = tid & 63;
  const int l16 = lane & 15, quad = lane >> 4;
  const int wr = w >> 1, wc = w & 1;
#pragma unroll
  for (int mi = 0; mi < 4; ++mi)
#pragma unroll
    for (int ni = 0; ni < 4; ++ni)
#pragma unroll
      for (int r = 0; r < 4; ++r) {
        int grow = tileM + wr * 64 + mi * 16 + quad * 4 + r;
        int gcol = n0 + wc * 64 + ni * 16 + l16;
        out[(size_t)grow * HID + gcol] = acc[mi][ni][r];
      }
}

// ---------------- flash attention v6: 128 q-rows per block (verified round 5) ----------------
#define PSTR 72
__global__ __launch_bounds__(256, 3) void attn(const bf16* __restrict__ Qb,
                                               const bf16* __restrict__ Kb,
                                               const bf16* __restrict__ Vt,
                                               bf16* __restrict__ Ctx) {
  __shared__ bf16 Ktile[2][64 * 64];
  __shared__ bf16 Vtile[2][64 * 64];
  __shared__ bf16 Pbuf[4][32 * PSTR];   // per wave: rows 0-15 = A, 16-31 = B
  const int tid = threadIdx.x;
  const int w = tid >> 6, lane = tid & 63;
  const int l16 = lane & 15, quad = lane >> 4;
  const int bh = blockIdx.y, b = bh >> 5, h = bh & 31, kvh = h >> 2;
  bf16* Pw = &Pbuf[w][0];
  const char* Kslice = (const char*)(Kb + ((size_t)(b * NKV + kvh)) * SS * HD);
  const char* Vslice = (const char*)(Vt + ((size_t)(b * NKV + kvh)) * HD * SS);
  const int qrel = w * 16 + l16;        // 0..63 within each 64-row subtile

  const int srow = (lane >> 3) & 7;
  const int pchunk = ((lane & 7) ^ srow) << 4;
  const int so = ((quad ^ (l16 & 7)) << 4);
  const int so2 = so ^ 64;

  const int xA = (int)blockIdx.x;       // 0..7

  int cur = 0;
  {
#pragma unroll
    for (int i = 0; i < 2; ++i) {
      const int r = w * 16 + i * 8 + srow;
      load_lds16(Kslice + (size_t)r * 128 + pchunk,
                 (char*)Ktile[0] + (w * 16 + i * 8) * 128);
      load_lds16(Vslice + (size_t)r * 4096 + pchunk,
                 (char*)Vtile[0] + (w * 16 + i * 8) * 128);
    }
  }

  for (int t = 0; t < 2; ++t) {
    const int X = t ? (15 - xA) : xA;   // 128-row superblock index
    const int qA = X * 128 + qrel;
    const int ktmax = 2 * X + 1;        // last kv tile (64 keys each)

    const bf16* QpA = Qb + ((size_t)(b * SS + qA)) * HID + h * HD + quad * 8;
    bf16x8 qa0 = *(const bf16x8*)QpA;
    bf16x8 qa1 = *(const bf16x8*)(QpA + 32);
    const bf16* QpB = QpA + (size_t)64 * HID;
    bf16x8 qbB0 = *(const bf16x8*)QpB;
    bf16x8 qbB1 = *(const bf16x8*)(QpB + 32);

    float lA = 0.f, lB = 0.f;
    f32x4 oA[4], oB[4];
#pragma unroll
    for (int d = 0; d < 4; ++d) {
      oA[d] = (f32x4){0.f, 0.f, 0.f, 0.f};
      oB[d] = (f32x4){0.f, 0.f, 0.f, 0.f};
    }

    for (int kt = 0; kt <= ktmax; ++kt) {
      __syncthreads();   // cur tile ready (staged a full compute phase ago)

      const bool have_next = (kt < ktmax) || (t == 0);
      if (have_next) {
        const int nkb = (kt < ktmax) ? (kt + 1) * 64 : 0;  // last: tile 0 for pass 1
        const int nb = cur ^ 1;
#pragma unroll
        for (int i = 0; i < 2; ++i) {
          const int r = w * 16 + i * 8 + srow;
          load_lds16(Kslice + (size_t)(nkb + r) * 128 + pchunk,
                     (char*)Ktile[nb] + (w * 16 + i * 8) * 128);
          load_lds16(Vslice + (size_t)r * 4096 + (size_t)nkb * 2 + pchunk,
                     (char*)Vtile[nb] + (w * 16 + i * 8) * 128);
        }
      }

      const char* Kc = (const char*)Ktile[cur] + l16 * 128;
      const char* Vc = (const char*)Vtile[cur] + l16 * 128;
      const bool skipA = (kt == ktmax);       // A fully masked on last tile
      const bool diagA = (kt == ktmax - 1);   // kt == 2X
      const bool diagB = (kt == ktmax);       // kt == 2X+1

#pragma unroll
      for (int nt = 0; nt < 4; ++nt) {
        bf16x8 kf0 = *(const bf16x8*)(Kc + nt * 2048 + so);
        bf16x8 kf1 = *(const bf16x8*)(Kc + nt * 2048 + so2);
        const int krel = nt * 16 + quad * 4;

        bf16x4 pkA;
        if (skipA) {
          pkA[0] = (bf16)0.f; pkA[1] = (bf16)0.f;
          pkA[2] = (bf16)0.f; pkA[3] = (bf16)0.f;
        } else {
          f32x4 s = {0.f, 0.f, 0.f, 0.f};
          s = MFMA16(kf0, qa0, s);   // S^T: row = key, col = q (l16)
          s = MFMA16(kf1, qa1, s);
          if (diagA) {
#pragma unroll
            for (int r = 0; r < 4; ++r) {
              float p = (krel + r > qrel) ? 0.f : __builtin_amdgcn_exp2f(s[r]);
              lA += p;
              pkA[r] = (bf16)p;
            }
          } else {
#pragma unroll
            for (int r = 0; r < 4; ++r) {
              float p = __builtin_amdgcn_exp2f(s[r]);
              lA += p;
              pkA[r] = (bf16)p;
            }
          }
        }
        *(bf16x4*)&Pw[l16 * PSTR + krel] = pkA;

        f32x4 sB = {0.f, 0.f, 0.f, 0.f};
        sB = MFMA16(kf0, qbB0, sB);
        sB = MFMA16(kf1, qbB1, sB);
        bf16x4 pkB;
        if (diagB) {
#pragma unroll
          for (int r = 0; r < 4; ++r) {
            float p = (krel + r > qrel) ? 0.f : __builtin_amdgcn_exp2f(sB[r]);
            lB += p;
            pkB[r] = (bf16)p;
          }
        } else {
#pragma unroll
          for (int r = 0; r < 4; ++r) {
            float p = __builtin_amdgcn_exp2f(sB[r]);
            lB += p;
            pkB[r] = (bf16)p;
          }
        }
        *(bf16x4*)&Pw[(16 + l16) * PSTR + krel] = pkB;
      }

      bf16x8 pA0 = *(const bf16x8*)&Pw[l16 * PSTR + quad * 8];
      bf16x8 pA1 = *(const bf16x8*)&Pw[l16 * PSTR + 32 + quad * 8];
      bf16x8 pB0 = *(const bf16x8*)&Pw[(16 + l16) * PSTR + quad * 8];
      bf16x8 pB1 = *(const bf16x8*)&Pw[(16 + l16) * PSTR + 32 + quad * 8];
#pragma unroll
      for (int dn = 0; dn < 4; ++dn) {
        bf16x8 v0 = *(const bf16x8*)(Vc + dn * 2048 + so);
        bf16x8 v1 = *(const bf16x8*)(Vc + dn * 2048 + so2);
        oA[dn] = MFMA16(v0, pA0, oA[dn]);  // O^T: row = d, col = q
        oA[dn] = MFMA16(v1, pA1, oA[dn]);
        oB[dn] = MFMA16(v0, pB0, oB[dn]);
        oB[dn] = MFMA16(v1, pB1, oB[dn]);
      }
      cur ^= 1;
    }

    lA += __shfl_xor(lA, 16);
    lA += __shfl_xor(lA, 32);
    lB += __shfl_xor(lB, 16);
    lB += __shfl_xor(lB, 32);
    const float invA = 1.0f / lA;
    const float invB = 1.0f / lB;
    bf16* CpA = Ctx + ((size_t)(b * SS + qA)) * HID + h * HD + quad * 4;
    bf16* CpB = CpA + (size_t)64 * HID;
#pragma unroll
    for (int dn = 0; dn < 4; ++dn) {
      bf16x4 ovA, ovB;
#pragma unroll
      for (int r = 0; r < 4; ++r) {
        ovA[r] = (bf16)(oA[dn][r] * invA);
        ovB[r] = (bf16)(oB[dn][r] * invB);
      }
      *(bf16x4*)(CpA + dn * 16) = ovA;
      *(bf16x4*)(CpB + dn * 16) = ovB;
    }
  }
}

// ---------------- launch ----------------
extern "C" void kernel_launch(void* const* d_in, const int* in_sizes, int n_in,
                              void* d_out, int out_size, void* d_ws, size_t ws_size,
                              hipStream_t stream) {
  const float* hs = (const float*)d_in[0];
  const float* Wq = (const float*)d_in[2];
  const float* Wk = (const float*)d_in[3];
  const float* Wv = (const float*)d_in[4];
  const float* Wo = (const float*)d_in[5];

  char* ws = (char*)d_ws;
  bf16* A_b  = (bf16*)(ws);              // 16 MB ; reused as Ctx after QKV gemm
  bf16* Wq_b = (bf16*)(ws + 16777216);   // 8 MB
  bf16* Wk_b = (bf16*)(ws + 25165824);   // 2 MB
  bf16* Wv_b = (bf16*)(ws + 27262976);   // 2 MB
  bf16* Wo_b = (bf16*)(ws + 29360128);   // 8 MB
  bf16* Qb   = (bf16*)(ws + 37748736);   // 16 MB
  bf16* Kb   = (bf16*)(ws + 54525952);   // 4 MB
  bf16* Vt   = (bf16*)(ws + 58720256);   // 4 MB  (end: 62914560)
  bf16* Ctx  = A_b;

  cvt_all<<<CVT_BLOCKS, 256, 0, stream>>>(hs, Wq, Wk, Wv, Wo, A_b, Wq_b, Wk_b, Wv_b, Wo_b);
  gemm_qkv<<<dim3(MTOT / 256, 24), 512, 0, stream>>>(A_b, Wq_b, Wk_b, Wv_b, Qb, Kb, Vt);
  attn<<<dim3(8, BB * NH), 256, 0, stream>>>(Qb, Kb, Vt, Ctx);
  gemm_out<<<dim3(MTOT / 256, HID / 128), 512, 0, stream>>>(Ctx, Wo_b, (float*)d_out);
}

// Round 10
// 289.771 us; speedup vs baseline: 1.0284x; 1.0082x over previous
//
#include <hip/hip_runtime.h>
#include <math.h>

#define HID 2048
#define NH 32
#define NKV 8
#define HD 64
#define BB 2
#define SS 2048
#define MTOT (BB * SS) // 4096

typedef __bf16 bf16;
typedef __bf16 bf16x8 __attribute__((ext_vector_type(8)));
typedef __bf16 bf16x4 __attribute__((ext_vector_type(4)));
typedef float f32x4 __attribute__((ext_vector_type(4)));

#define MFMA16(a, b, c) __builtin_amdgcn_mfma_f32_16x16x32_bf16((a), (b), (c), 0, 0, 0)

__device__ __forceinline__ void load_lds16(const void* g, void* l) {
  __builtin_amdgcn_global_load_lds((const __attribute__((address_space(1))) void*)g,
                                   (__attribute__((address_space(3))) void*)l, 16, 0, 0);
}

#define FENCE() asm volatile("" ::: "memory")
// Tile-top sync: counted vmcnt (never 0 in main loop) + lgkmcnt(0) so this
// wave's ds_reads have COMPLETED before it enters the barrier (orders them
// against other waves' post-barrier global_load_lds writebacks), then barrier.
#define SYNC_VM(N) do { FENCE(); \
  asm volatile("s_waitcnt vmcnt(" #N ") lgkmcnt(0)" ::: "memory"); \
  __builtin_amdgcn_s_barrier(); FENCE(); } while (0)

// ---------------- fused fp32 -> bf16 convert (EXACT R0 version - fastest measured) ----------------
// R6<->R8 clean A/B: this 18432-tiny-block one-load-per-thread form is 34 us
// FASTER than both the 8-elem (R8) and grid-stride (R9) variants. The many
// small blocks give free block-level MLP; each wave's single load issues
// immediately. Do not "optimize" this again without a same-round A/B.
// segments in blocks of 1024 elements: hs 8192 | Wq 4096 | Wk 1024 | Wv 1024 | Wo 4096
__global__ void cvt_all(const float* __restrict__ hs, const float* __restrict__ Wq,
                        const float* __restrict__ Wk, const float* __restrict__ Wv,
                        const float* __restrict__ Wo,
                        bf16* __restrict__ A_b, bf16* __restrict__ Wq_b,
                        bf16* __restrict__ Wk_b, bf16* __restrict__ Wv_b,
                        bf16* __restrict__ Wo_b) {
  int bid = blockIdx.x;
  const float* src;
  bf16* dst;
  if (bid < 8192)       { src = hs; dst = A_b; }
  else if (bid < 12288) { src = Wq; dst = Wq_b; bid -= 8192; }
  else if (bid < 13312) { src = Wk; dst = Wk_b; bid -= 12288; }
  else if (bid < 14336) { src = Wv; dst = Wv_b; bid -= 13312; }
  else                  { src = Wo; dst = Wo_b; bid -= 14336; }
  int i = (bid * 256 + threadIdx.x) * 4;
  float4 v = *(const float4*)(src + i);
  bf16x4 o;
  o[0] = (bf16)v.x; o[1] = (bf16)v.y; o[2] = (bf16)v.z; o[3] = (bf16)v.w;
  *(bf16x4*)(dst + i) = o;
}

// ---------------- BK=32 pipelined core (verified round 4/5): 256x128, 8 waves ----------------
// 72 KB -> 2 WG/CU (16 waves) -- the best measured waves/CU config for qkv.
__device__ __forceinline__ void gemm_core256x128(const char* Agc, const char* Bgc,
                                                 char* lds, f32x4 (&acc)[4][4]) {
  constexpr int ABYTES = 16384;     // A tile bytes (256 x 32 bf16)
  constexpr int BUFB = 24576;       // + B tile (128 x 32 bf16)
  constexpr int NT = HID / 32;      // 64 K-tiles

  const int tid = threadIdx.x;
  const int w = tid >> 6, lane = tid & 63;
  const int l16 = lane & 15, quad = lane >> 4;
  const int wr = w >> 1, wc = w & 1;
  const int wb = w * 1024;          // wave-uniform LDS staging base

  const int cu = (tid & 7) ^ ((tid >> 3) & 7);
  const int srcR0 = 2 * (tid >> 3) + (cu >> 2);   // 0..127
  const int srcC = (cu & 3) * 16;
  const char* gA = Agc + (size_t)srcR0 * (HID * 2) + srcC;
  const char* gB = Bgc + (size_t)srcR0 * (HID * 2) + srcC;

  const int acg16 = ((((l16 & 1) << 2) | quad) ^ ((l16 >> 1) & 7)) * 16;
  const int aoff = (wr * 32 + (l16 >> 1)) * 128 + acg16;
  const int boff = ABYTES + (wc * 32 + (l16 >> 1)) * 128 + acg16;

#pragma unroll
  for (int t0 = 0; t0 < 2; ++t0) {
    char* lb = lds + t0 * BUFB;
    load_lds16(gA + t0 * 64, lb + wb);
    load_lds16(gA + (size_t)128 * (HID * 2) + t0 * 64, lb + 8192 + wb);
    load_lds16(gB + t0 * 64, lb + ABYTES + wb);
  }

  char* cur = lds;
  char* stg = lds + 2 * BUFB;
  for (int kt = 0; kt < NT; ++kt) {
    SYNC_VM(3);
    const int ks = (kt + 2 < NT) ? (kt + 2) * 64 : (NT - 1) * 64;

    load_lds16(gA + ks, stg + wb);
    load_lds16(gA + (size_t)128 * (HID * 2) + ks, stg + 8192 + wb);
    load_lds16(gB + ks, stg + ABYTES + wb);
    FENCE();

    bf16x8 af[4], bfr[4];
#pragma unroll
    for (int ni = 0; ni < 4; ++ni)
      bfr[ni] = *(const bf16x8*)(cur + boff + ni * 1024);
#pragma unroll
    for (int mi = 0; mi < 4; ++mi)
      af[mi] = *(const bf16x8*)(cur + aoff + mi * 1024);
    __builtin_amdgcn_s_setprio(1);
#pragma unroll
    for (int mi = 0; mi < 4; ++mi)
#pragma unroll
      for (int ni = 0; ni < 4; ++ni)
        acc[mi][ni] = MFMA16(af[mi], bfr[ni], acc[mi][ni]);
    __builtin_amdgcn_s_setprio(0);

    cur = (cur == lds + 2 * BUFB) ? lds : cur + BUFB;
    stg = (stg == lds + 2 * BUFB) ? lds : stg + BUFB;
  }
  asm volatile("s_waitcnt vmcnt(0)" ::: "memory");
}

// ---------------- BK=64 single-phase core (verified round 6; best at full fill) ----------------
// 3 rotating 48 KB buffers (144 KB -> 1 WG/CU), SYNC_VM(6) at step top, one
// barrier per K-step, 32 MFMA/wave/step. (The round-7 2-phase variant
// regressed ~1.7x -- coarse split without fine interleave. Do not re-add.)
__device__ __forceinline__ void gemm_core_k64(const char* Agc, const char* Bgc,
                                              char* lds, f32x4 (&acc)[4][4]) {
  constexpr int ABYTES = 32768;   // A tile: 256 rows x 64 cols bf16
  constexpr int BUFB = 49152;     // + B tile: 128 rows x 64 cols bf16
  constexpr int NT = HID / 64;    // 32 K-steps

  const int tid = threadIdx.x;
  const int w = tid >> 6, lane = tid & 63;
  const int l16 = lane & 15, quad = lane >> 4;
  const int wr = w >> 1, wc = w & 1;
  const int wb = w * 1024;        // wave-uniform LDS staging base

  // staging: wave w, load j -> row = w*8 + j*64 + (lane>>3),
  // logical chunk = (lane&7) ^ ((lane>>3)&7); inverse swizzle on global src.
  const int cu = (lane & 7) ^ ((lane >> 3) & 7);
  const char* gA = Agc + (size_t)(w * 8 + (lane >> 3)) * 4096 + cu * 16;
  const char* gB = Bgc + (size_t)(w * 8 + (lane >> 3)) * 4096 + cu * 16;

  // ds_read: row r chunk c at (c ^ (r&7))*16
  const int aswz = l16 & 7;
  const int a_k0 = ((0 + quad) ^ aswz) * 16;   // ks = 0
  const int a_k1 = ((4 + quad) ^ aswz) * 16;   // ks = 1
  const int arow = (wr * 64 + l16) * 128;
  const int brow = (wc * 64 + l16) * 128;

  // prologue: stage K-steps 0 and 1 (6 loads per wave per K-step: 4 A + 2 B)
#pragma unroll
  for (int t0 = 0; t0 < 2; ++t0) {
    char* lb = lds + t0 * BUFB;
#pragma unroll
    for (int j = 0; j < 4; ++j)
      load_lds16(gA + (size_t)j * (64 * 4096) + t0 * 128, lb + wb + j * 8192);
#pragma unroll
    for (int j = 0; j < 2; ++j)
      load_lds16(gB + (size_t)j * (64 * 4096) + t0 * 128, lb + ABYTES + wb + j * 8192);
  }

  char* cur = lds;
  char* stg = lds + 2 * BUFB;
  for (int kt = 0; kt < NT; ++kt) {
    SYNC_VM(6);
    const int ks = (kt + 2 < NT) ? (kt + 2) : (NT - 1);
    const size_t ko = (size_t)ks * 128;

#pragma unroll
    for (int j = 0; j < 4; ++j)
      load_lds16(gA + (size_t)j * (64 * 4096) + ko, stg + wb + j * 8192);
#pragma unroll
    for (int j = 0; j < 2; ++j)
      load_lds16(gB + (size_t)j * (64 * 4096) + ko, stg + ABYTES + wb + j * 8192);
    FENCE();

    const char* Ac = cur;
    const char* Bc = cur + ABYTES;
    bf16x8 af0[4], af1[4], bf0[4], bf1[4];
#pragma unroll
    for (int ni = 0; ni < 4; ++ni) {
      bf0[ni] = *(const bf16x8*)(Bc + brow + ni * 2048 + a_k0);
      bf1[ni] = *(const bf16x8*)(Bc + brow + ni * 2048 + a_k1);
    }
#pragma unroll
    for (int mi = 0; mi < 4; ++mi) {
      af0[mi] = *(const bf16x8*)(Ac + arow + mi * 2048 + a_k0);
      af1[mi] = *(const bf16x8*)(Ac + arow + mi * 2048 + a_k1);
    }
    __builtin_amdgcn_s_setprio(1);
#pragma unroll
    for (int mi = 0; mi < 4; ++mi)
#pragma unroll
      for (int ni = 0; ni < 4; ++ni) {
        acc[mi][ni] = MFMA16(af0[mi], bf0[ni], acc[mi][ni]);
        acc[mi][ni] = MFMA16(af1[mi], bf1[ni], acc[mi][ni]);
      }
    __builtin_amdgcn_s_setprio(0);

    cur = (cur == lds + 2 * BUFB) ? lds : cur + BUFB;
    stg = (stg == lds + 2 * BUFB) ? lds : stg + BUFB;
  }
  asm volatile("s_waitcnt vmcnt(0)" ::: "memory");
}

// ---------------- fused QKV projection + RoPE epilogue (verified R5/R7) ----------------
#define QSCALE 0.1803368801f
#define L2B 0.4152410118f  // log2(10000)/32
__global__ __launch_bounds__(512, 4) void gemm_qkv(const bf16* __restrict__ A,
                                                   const bf16* __restrict__ Wq,
                                                   const bf16* __restrict__ Wk,
                                                   const bf16* __restrict__ Wv,
                                                   bf16* __restrict__ Qb,
                                                   bf16* __restrict__ Kb,
                                                   bf16* __restrict__ Vt) {
  __shared__ __align__(16) char lds[3 * 24576];  // 72 KB -> 2 WG/CU (16 waves)
  const int tileM = blockIdx.x * 256;
  const int n0 = blockIdx.y * 128;
  const bf16* Wp;
  int mode;
  if (n0 < HID) { Wp = Wq + (size_t)n0 * HID; mode = 0; }
  else if (n0 < HID + 512) { Wp = Wk + (size_t)(n0 - HID) * HID; mode = 1; }
  else { Wp = Wv + (size_t)(n0 - HID - 512) * HID; mode = 2; }

  f32x4 acc[4][4];
#pragma unroll
  for (int i = 0; i < 4; ++i)
#pragma unroll
    for (int j = 0; j < 4; ++j) acc[i][j] = (f32x4){0.f, 0.f, 0.f, 0.f};

  gemm_core256x128((const char*)(A + (size_t)tileM * HID), (const char*)Wp, lds, acc);

  const int tid = threadIdx.x;
  const int w = tid >> 6, lane = tid & 63;
  const int l16 = lane & 15, quad = lane >> 4;
  const int wr = w >> 1, wc = w & 1;
  const int mbase = tileM + wr * 64;
  const int cb = n0 + wc * 64;  // 64-aligned -> wave col span = one head

  if (mode == 2) {
    // V: transposed layout [b,kvh,d,s]
#pragma unroll
    for (int mi = 0; mi < 4; ++mi)
#pragma unroll
      for (int ni = 0; ni < 4; ++ni)
#pragma unroll
        for (int r = 0; r < 4; ++r) {
          int grow = mbase + mi * 16 + quad * 4 + r;
          int b = grow >> 11, spos = grow & (SS - 1);
          int nv = cb + ni * 16 + l16 - (HID + 512);
          Vt[(((size_t)(b * NKV + (nv >> 6))) * HD + (nv & 63)) * SS + spos] =
              (bf16)acc[mi][ni][r];
        }
  } else {
    // Q or K: RoPE in fp32 regs; pairs (ni=0,ni=2) at freq l16, (1,3) at l16+16.
    const float inv0 = __builtin_amdgcn_exp2f(-(float)l16 * L2B);
    const float inv1 = __builtin_amdgcn_exp2f(-(float)(l16 + 16) * L2B);
#pragma unroll
    for (int mi = 0; mi < 4; ++mi) {
#pragma unroll
      for (int r = 0; r < 4; ++r) {
        int grow = mbase + mi * 16 + quad * 4 + r;
        int b = grow >> 11, spos = grow & (SS - 1);
        float sn0, cs0, sn1, cs1;
        sincosf((float)spos * inv0, &sn0, &cs0);
        sincosf((float)spos * inv1, &sn1, &cs1);
        float a0 = acc[mi][0][r], a1 = acc[mi][1][r];
        float a2 = acc[mi][2][r], a3 = acc[mi][3][r];
        float o0 = a0 * cs0 - a2 * sn0;
        float o2 = a2 * cs0 + a0 * sn0;
        float o1 = a1 * cs1 - a3 * sn1;
        float o3 = a3 * cs1 + a1 * sn1;
        if (mode == 0) {
          bf16* qp = Qb + (size_t)grow * HID + cb + l16;
          qp[0]  = (bf16)(o0 * QSCALE);
          qp[16] = (bf16)(o1 * QSCALE);
          qp[32] = (bf16)(o2 * QSCALE);
          qp[48] = (bf16)(o3 * QSCALE);
        } else {
          int kvh = (cb - HID) >> 6;
          bf16* kp = Kb + ((size_t)(b * NKV + kvh) * SS + spos) * HD + l16;
          kp[0]  = (bf16)o0;
          kp[16] = (bf16)o1;
          kp[32] = (bf16)o2;
          kp[48] = (bf16)o3;
        }
      }
    }
  }
}

// ---------------- output projection (grid 16x16 = 256 blocks = 1/CU, BK=64 single-phase) ----------------
__global__ __launch_bounds__(512, 2) void gemm_out(const bf16* __restrict__ A,
                                                   const bf16* __restrict__ Wo,
                                                   float* __restrict__ out) {
  __shared__ __align__(16) char lds[3 * 49152];  // 144 KB -> 1 WG/CU
  const int tileM = blockIdx.x * 256;
  const int n0 = blockIdx.y * 128;
  f32x4 acc[4][4];
#pragma unroll
  for (int i = 0; i < 4; ++i)
#pragma unroll
    for (int j = 0; j < 4; ++j) acc[i][j] = (f32x4){0.f, 0.f, 0.f, 0.f};

  gemm_core_k64((const char*)(A + (size_t)tileM * HID),
                (const char*)(Wo + (size_t)n0 * HID), lds, acc);

  const int tid = threadIdx.x;
  const int w = tid >> 6, lane = tid & 63;
  const int l16 = lane & 15, quad = lane >> 4;
  const int wr = w >> 1, wc = w & 1;
#pragma unroll
  for (int mi = 0; mi < 4; ++mi)
#pragma unroll
    for (int ni = 0; ni < 4; ++ni)
#pragma unroll
      for (int r = 0; r < 4; ++r) {
        int grow = tileM + wr * 64 + mi * 16 + quad * 4 + r;
        int gcol = n0 + wc * 64 + ni * 16 + l16;
        out[(size_t)grow * HID + gcol] = acc[mi][ni][r];
      }
}

// ---------------- flash attention v6: 128 q-rows per block (verified round 5) ----------------
#define PSTR 72
__global__ __launch_bounds__(256, 3) void attn(const bf16* __restrict__ Qb,
                                               const bf16* __restrict__ Kb,
                                               const bf16* __restrict__ Vt,
                                               bf16* __restrict__ Ctx) {
  __shared__ bf16 Ktile[2][64 * 64];
  __shared__ bf16 Vtile[2][64 * 64];
  __shared__ bf16 Pbuf[4][32 * PSTR];   // per wave: rows 0-15 = A, 16-31 = B
  const int tid = threadIdx.x;
  const int w = tid >> 6, lane = tid & 63;
  const int l16 = lane & 15, quad = lane >> 4;
  const int bh = blockIdx.y, b = bh >> 5, h = bh & 31, kvh = h >> 2;
  bf16* Pw = &Pbuf[w][0];
  const char* Kslice = (const char*)(Kb + ((size_t)(b * NKV + kvh)) * SS * HD);
  const char* Vslice = (const char*)(Vt + ((size_t)(b * NKV + kvh)) * HD * SS);
  const int qrel = w * 16 + l16;        // 0..63 within each 64-row subtile

  const int srow = (lane >> 3) & 7;
  const int pchunk = ((lane & 7) ^ srow) << 4;
  const int so = ((quad ^ (l16 & 7)) << 4);
  const int so2 = so ^ 64;

  const int xA = (int)blockIdx.x;       // 0..7

  int cur = 0;
  {
#pragma unroll
    for (int i = 0; i < 2; ++i) {
      const int r = w * 16 + i * 8 + srow;
      load_lds16(Kslice + (size_t)r * 128 + pchunk,
                 (char*)Ktile[0] + (w * 16 + i * 8) * 128);
      load_lds16(Vslice + (size_t)r * 4096 + pchunk,
                 (char*)Vtile[0] + (w * 16 + i * 8) * 128);
    }
  }

  for (int t = 0; t < 2; ++t) {
    const int X = t ? (15 - xA) : xA;   // 128-row superblock index
    const int qA = X * 128 + qrel;
    const int ktmax = 2 * X + 1;        // last kv tile (64 keys each)

    const bf16* QpA = Qb + ((size_t)(b * SS + qA)) * HID + h * HD + quad * 8;
    bf16x8 qa0 = *(const bf16x8*)QpA;
    bf16x8 qa1 = *(const bf16x8*)(QpA + 32);
    const bf16* QpB = QpA + (size_t)64 * HID;
    bf16x8 qbB0 = *(const bf16x8*)QpB;
    bf16x8 qbB1 = *(const bf16x8*)(QpB + 32);

    float lA = 0.f, lB = 0.f;
    f32x4 oA[4], oB[4];
#pragma unroll
    for (int d = 0; d < 4; ++d) {
      oA[d] = (f32x4){0.f, 0.f, 0.f, 0.f};
      oB[d] = (f32x4){0.f, 0.f, 0.f, 0.f};
    }

    for (int kt = 0; kt <= ktmax; ++kt) {
      __syncthreads();   // cur tile ready (staged a full compute phase ago)

      const bool have_next = (kt < ktmax) || (t == 0);
      if (have_next) {
        const int nkb = (kt < ktmax) ? (kt + 1) * 64 : 0;  // last: tile 0 for pass 1
        const int nb = cur ^ 1;
#pragma unroll
        for (int i = 0; i < 2; ++i) {
          const int r = w * 16 + i * 8 + srow;
          load_lds16(Kslice + (size_t)(nkb + r) * 128 + pchunk,
                     (char*)Ktile[nb] + (w * 16 + i * 8) * 128);
          load_lds16(Vslice + (size_t)r * 4096 + (size_t)nkb * 2 + pchunk,
                     (char*)Vtile[nb] + (w * 16 + i * 8) * 128);
        }
      }

      const char* Kc = (const char*)Ktile[cur] + l16 * 128;
      const char* Vc = (const char*)Vtile[cur] + l16 * 128;
      const bool skipA = (kt == ktmax);       // A fully masked on last tile
      const bool diagA = (kt == ktmax - 1);   // kt == 2X
      const bool diagB = (kt == ktmax);       // kt == 2X+1

#pragma unroll
      for (int nt = 0; nt < 4; ++nt) {
        bf16x8 kf0 = *(const bf16x8*)(Kc + nt * 2048 + so);
        bf16x8 kf1 = *(const bf16x8*)(Kc + nt * 2048 + so2);
        const int krel = nt * 16 + quad * 4;

        bf16x4 pkA;
        if (skipA) {
          pkA[0] = (bf16)0.f; pkA[1] = (bf16)0.f;
          pkA[2] = (bf16)0.f; pkA[3] = (bf16)0.f;
        } else {
          f32x4 s = {0.f, 0.f, 0.f, 0.f};
          s = MFMA16(kf0, qa0, s);   // S^T: row = key, col = q (l16)
          s = MFMA16(kf1, qa1, s);
          if (diagA) {
#pragma unroll
            for (int r = 0; r < 4; ++r) {
              float p = (krel + r > qrel) ? 0.f : __builtin_amdgcn_exp2f(s[r]);
              lA += p;
              pkA[r] = (bf16)p;
            }
          } else {
#pragma unroll
            for (int r = 0; r < 4; ++r) {
              float p = __builtin_amdgcn_exp2f(s[r]);
              lA += p;
              pkA[r] = (bf16)p;
            }
          }
        }
        *(bf16x4*)&Pw[l16 * PSTR + krel] = pkA;

        f32x4 sB = {0.f, 0.f, 0.f, 0.f};
        sB = MFMA16(kf0, qbB0, sB);
        sB = MFMA16(kf1, qbB1, sB);
        bf16x4 pkB;
        if (diagB) {
#pragma unroll
          for (int r = 0; r < 4; ++r) {
            float p = (krel + r > qrel) ? 0.f : __builtin_amdgcn_exp2f(sB[r]);
            lB += p;
            pkB[r] = (bf16)p;
          }
        } else {
#pragma unroll
          for (int r = 0; r < 4; ++r) {
            float p = __builtin_amdgcn_exp2f(sB[r]);
            lB += p;
            pkB[r] = (bf16)p;
          }
        }
        *(bf16x4*)&Pw[(16 + l16) * PSTR + krel] = pkB;
      }

      bf16x8 pA0 = *(const bf16x8*)&Pw[l16 * PSTR + quad * 8];
      bf16x8 pA1 = *(const bf16x8*)&Pw[l16 * PSTR + 32 + quad * 8];
      bf16x8 pB0 = *(const bf16x8*)&Pw[(16 + l16) * PSTR + quad * 8];
      bf16x8 pB1 = *(const bf16x8*)&Pw[(16 + l16) * PSTR + 32 + quad * 8];
#pragma unroll
      for (int dn = 0; dn < 4; ++dn) {
        bf16x8 v0 = *(const bf16x8*)(Vc + dn * 2048 + so);
        bf16x8 v1 = *(const bf16x8*)(Vc + dn * 2048 + so2);
        oA[dn] = MFMA16(v0, pA0, oA[dn]);  // O^T: row = d, col = q
        oA[dn] = MFMA16(v1, pA1, oA[dn]);
        oB[dn] = MFMA16(v0, pB0, oB[dn]);
        oB[dn] = MFMA16(v1, pB1, oB[dn]);
      }
      cur ^= 1;
    }

    lA += __shfl_xor(lA, 16);
    lA += __shfl_xor(lA, 32);
    lB += __shfl_xor(lB, 16);
    lB += __shfl_xor(lB, 32);
    const float invA = 1.0f / lA;
    const float invB = 1.0f / lB;
    bf16* CpA = Ctx + ((size_t)(b * SS + qA)) * HID + h * HD + quad * 4;
    bf16* CpB = CpA + (size_t)64 * HID;
#pragma unroll
    for (int dn = 0; dn < 4; ++dn) {
      bf16x4 ovA, ovB;
#pragma unroll
      for (int r = 0; r < 4; ++r) {
        ovA[r] = (bf16)(oA[dn][r] * invA);
        ovB[r] = (bf16)(oB[dn][r] * invB);
      }
      *(bf16x4*)(CpA + dn * 16) = ovA;
      *(bf16x4*)(CpB + dn * 16) = ovB;
    }
  }
}

// ---------------- launch ----------------
extern "C" void kernel_launch(void* const* d_in, const int* in_sizes, int n_in,
                              void* d_out, int out_size, void* d_ws, size_t ws_size,
                              hipStream_t stream) {
  const float* hs = (const float*)d_in[0];
  const float* Wq = (const float*)d_in[2];
  const float* Wk = (const float*)d_in[3];
  const float* Wv = (const float*)d_in[4];
  const float* Wo = (const float*)d_in[5];

  char* ws = (char*)d_ws;
  bf16* A_b  = (bf16*)(ws);              // 16 MB ; reused as Ctx after QKV gemm
  bf16* Wq_b = (bf16*)(ws + 16777216);   // 8 MB
  bf16* Wk_b = (bf16*)(ws + 25165824);   // 2 MB
  bf16* Wv_b = (bf16*)(ws + 27262976);   // 2 MB
  bf16* Wo_b = (bf16*)(ws + 29360128);   // 8 MB
  bf16* Qb   = (bf16*)(ws + 37748736);   // 16 MB
  bf16* Kb   = (bf16*)(ws + 54525952);   // 4 MB
  bf16* Vt   = (bf16*)(ws + 58720256);   // 4 MB  (end: 62914560)
  bf16* Ctx  = A_b;

  cvt_all<<<18432, 256, 0, stream>>>(hs, Wq, Wk, Wv, Wo, A_b, Wq_b, Wk_b, Wv_b, Wo_b);
  gemm_qkv<<<dim3(MTOT / 256, 24), 512, 0, stream>>>(A_b, Wq_b, Wk_b, Wv_b, Qb, Kb, Vt);
  attn<<<dim3(8, BB * NH), 256, 0, stream>>>(Qb, Kb, Vt, Ctx);
  gemm_out<<<dim3(MTOT / 256, HID / 128), 512, 0, stream>>>(Ctx, Wo_b, (float*)d_out);
}